// Round 2
// baseline (1321.386 us; speedup 1.0000x reference)
//
#include <hip/hip_runtime.h>
#include <math.h>

#define NB 2
#define NL 2048
#define ND 1024
#define NH 16
#define NDH 64

static constexpr int   QKV_ELEMS = NB * NH * NL * NDH;   // 4194304 floats per tensor
static constexpr float SCALE     = 0.125f;               // 1/sqrt(64)

// ---------------------------------------------------------------------------
// Kernel 1: QKV projection.  Q[b,h,l,k] = sum_d x[b,l,d] * W[h,d,k] + bias[h,k]
// One block: 64 rows (m) x 64 cols (one head's DH) of one of Q/K/V.
// ---------------------------------------------------------------------------
__global__ __launch_bounds__(256) void k_qkv(
    const float* __restrict__ x,
    const float* __restrict__ Wq, const float* __restrict__ bq,
    const float* __restrict__ Wk, const float* __restrict__ bk,
    const float* __restrict__ Wv, const float* __restrict__ bv,
    float* __restrict__ ws)
{
    __shared__ float As[64][36];   // x tile   [64 m][32 k], pad to 36 (16B-aligned, conflict-free reads)
    __shared__ float Bs[32][64];   // W tile   [32 k][64 n]

    const int mt  = blockIdx.x;        // 0..63
    const int qkv = blockIdx.y >> 4;   // 0..2
    const int h   = blockIdx.y & 15;   // 0..15

    const float* W    = (qkv == 0 ? Wq : (qkv == 1 ? Wk : Wv)) + (size_t)h * (ND * NDH);
    const float* bias = (qkv == 0 ? bq : (qkv == 1 ? bk : bv)) + h * NDH;
    float* out = ws + (size_t)qkv * QKV_ELEMS;

    const int t  = threadIdx.x;
    const int tx = t & 15;       // output col group
    const int ty = t >> 4;       // output row group

    float acc[4][4] = {};

    const int ar = t >> 2;            // 0..63  (A tile row)
    const int ac = (t & 3) * 8;       // 0,8,16,24
    const float* xsrc = x + (size_t)(mt * 64 + ar) * ND + ac;
    const int br = t >> 3;            // 0..31  (B tile k-row)
    const int bc = (t & 7) * 8;       // 0..56
    const float* wsrc = W + (size_t)br * NDH + bc;

    for (int k0 = 0; k0 < ND; k0 += 32) {
        __syncthreads();
        float4 a0 = *(const float4*)(xsrc + k0);
        float4 a1 = *(const float4*)(xsrc + k0 + 4);
        float4 b0 = *(const float4*)(wsrc + (size_t)k0 * NDH);
        float4 b1 = *(const float4*)(wsrc + (size_t)k0 * NDH + 4);
        *(float4*)&As[ar][ac]     = a0;
        *(float4*)&As[ar][ac + 4] = a1;
        *(float4*)&Bs[br][bc]     = b0;
        *(float4*)&Bs[br][bc + 4] = b1;
        __syncthreads();

#pragma unroll
        for (int kk = 0; kk < 32; ++kk) {
            float a[4];
#pragma unroll
            for (int r = 0; r < 4; ++r) a[r] = As[ty * 4 + r][kk];
            const float4 b4 = *(const float4*)&Bs[kk][tx * 4];
            const float bb[4] = {b4.x, b4.y, b4.z, b4.w};
#pragma unroll
            for (int r = 0; r < 4; ++r)
#pragma unroll
                for (int c = 0; c < 4; ++c)
                    acc[r][c] = fmaf(a[r], bb[c], acc[r][c]);
        }
    }

    const float4 bi4 = *(const float4*)(bias + tx * 4);
    const float bi[4] = {bi4.x, bi4.y, bi4.z, bi4.w};
#pragma unroll
    for (int r = 0; r < 4; ++r) {
        const int m = mt * 64 + ty * 4 + r;
        const int b = m >> 11;            // m / NL
        const int l = m & (NL - 1);
        float4 o;
        o.x = acc[r][0] + bi[0];
        o.y = acc[r][1] + bi[1];
        o.z = acc[r][2] + bi[2];
        o.w = acc[r][3] + bi[3];
        *(float4*)&out[(((size_t)(b * NH + h) * NL + l) << 6) + tx * 4] = o;
    }
}

// ---------------------------------------------------------------------------
// Kernel 2: column stats. Z[b,h,j] = sum_i exp(SCALE * Q_i . K_j)
// Block: one (b,h), one 64-wide j tile; streams all i tiles.
// ---------------------------------------------------------------------------
__global__ __launch_bounds__(256) void k_colsum(
    const float* __restrict__ ws, float* __restrict__ Zout)
{
    __shared__ float Kst[64][68];   // K^T tile: [d][j], pad 68 (16B aligned)
    __shared__ float Qst[64][68];   // Q^T tile: [d][i]
    __shared__ float Zred[16][64];

    const int jt = blockIdx.x;   // 0..31
    const int bh = blockIdx.y;   // 0..31
    const float* Qb = ws + (size_t)bh * NL * NDH;
    const float* Kb = ws + (size_t)QKV_ELEMS + (size_t)bh * NL * NDH;

    const int t  = threadIdx.x;
    const int tx = t & 15;   // j group
    const int ty = t >> 4;   // i group

    // stage K^T once (j tile is fixed for this block)
    {
        const int rr = t >> 2;           // 0..63 (j row)
        const int c4 = (t & 3) * 16;     // d offset
        const float* src = Kb + (size_t)(jt * 64 + rr) * NDH + c4;
        float4 v0 = *(const float4*)(src + 0);
        float4 v1 = *(const float4*)(src + 4);
        float4 v2 = *(const float4*)(src + 8);
        float4 v3 = *(const float4*)(src + 12);
        const float tmp[16] = {v0.x,v0.y,v0.z,v0.w, v1.x,v1.y,v1.z,v1.w,
                               v2.x,v2.y,v2.z,v2.w, v3.x,v3.y,v3.z,v3.w};
#pragma unroll
        for (int u = 0; u < 16; ++u) Kst[c4 + u][rr] = tmp[u];
    }

    float zacc[4] = {0.f, 0.f, 0.f, 0.f};

    for (int it = 0; it < 32; ++it) {
        __syncthreads();
        // stage Q^T for this i tile
        {
            const int rr = t >> 2;
            const int c4 = (t & 3) * 16;
            const float* src = Qb + (size_t)(it * 64 + rr) * NDH + c4;
            float4 v0 = *(const float4*)(src + 0);
            float4 v1 = *(const float4*)(src + 4);
            float4 v2 = *(const float4*)(src + 8);
            float4 v3 = *(const float4*)(src + 12);
            const float tmp[16] = {v0.x,v0.y,v0.z,v0.w, v1.x,v1.y,v1.z,v1.w,
                                   v2.x,v2.y,v2.z,v2.w, v3.x,v3.y,v3.z,v3.w};
#pragma unroll
            for (int u = 0; u < 16; ++u) Qst[c4 + u][rr] = tmp[u];
        }
        __syncthreads();

        float s[4][4] = {};
#pragma unroll 8
        for (int dd = 0; dd < 64; ++dd) {
            const float4 qa4 = *(const float4*)&Qst[dd][ty * 4];
            const float4 kb4 = *(const float4*)&Kst[dd][tx * 4];
            const float qa[4] = {qa4.x, qa4.y, qa4.z, qa4.w};
            const float kb[4] = {kb4.x, kb4.y, kb4.z, kb4.w};
#pragma unroll
            for (int r = 0; r < 4; ++r)
#pragma unroll
                for (int c = 0; c < 4; ++c)
                    s[r][c] = fmaf(qa[r], kb[c], s[r][c]);
        }
#pragma unroll
        for (int r = 0; r < 4; ++r)
#pragma unroll
            for (int c = 0; c < 4; ++c)
                zacc[c] += __expf(s[r][c] * SCALE);
    }

    __syncthreads();
#pragma unroll
    for (int c = 0; c < 4; ++c) Zred[ty][tx * 4 + c] = zacc[c];
    __syncthreads();
    if (t < 64) {
        float z = 0.f;
#pragma unroll
        for (int r = 0; r < 16; ++r) z += Zred[r][t];
        Zout[(size_t)bh * NL + jt * 64 + t] = z;
    }
}

// ---------------------------------------------------------------------------
// Kernel 3: O[i,k] = sum_j exp(SCALE * Q_i.K_j) / Z_j * V[j,k]
// Block: one (b,h), one 64-row i tile; streams j tiles; recomputes S.
// Output written head-concat: AO[b, l, h*64 + k]
// ---------------------------------------------------------------------------
__global__ __launch_bounds__(256) void k_av(const float* __restrict__ ws,
                                            float* __restrict__ AO)
{
    __shared__ float Qst[64][68];   // Q^T [d][i]
    __shared__ float Kst[64][68];   // K^T [d][j]
    __shared__ float Vs[64][64];    // V   [j][k]
    __shared__ float Pst[64][68];   // P^T [j][i]
    __shared__ float rzs[64];

    const int it = blockIdx.x;   // 0..31
    const int bh = blockIdx.y;   // 0..31
    const int b  = bh >> 4;
    const int h  = bh & 15;
    const float* Qb = ws + (size_t)bh * NL * NDH;
    const float* Kb = Qb + QKV_ELEMS;
    const float* Vb = Qb + 2 * (size_t)QKV_ELEMS;
    const float* Z  = ws + 3 * (size_t)QKV_ELEMS + (size_t)bh * NL;

    const int t  = threadIdx.x;
    const int tx = t & 15;   // k group (and j group in S phase)
    const int ty = t >> 4;   // i group

    // stage Q^T once (i tile fixed)
    {
        const int rr = t >> 2;
        const int c4 = (t & 3) * 16;
        const float* src = Qb + (size_t)(it * 64 + rr) * NDH + c4;
        float4 v0 = *(const float4*)(src + 0);
        float4 v1 = *(const float4*)(src + 4);
        float4 v2 = *(const float4*)(src + 8);
        float4 v3 = *(const float4*)(src + 12);
        const float tmp[16] = {v0.x,v0.y,v0.z,v0.w, v1.x,v1.y,v1.z,v1.w,
                               v2.x,v2.y,v2.z,v2.w, v3.x,v3.y,v3.z,v3.w};
#pragma unroll
        for (int u = 0; u < 16; ++u) Qst[c4 + u][rr] = tmp[u];
    }

    float acc[4][4] = {};

    for (int jt = 0; jt < 32; ++jt) {
        __syncthreads();   // previous iteration's Kst/Vs/Pst reads done (and Qst staged, iter 0)
        {
            const int rr = t >> 2;
            const int c4 = (t & 3) * 16;
            const float* src = Kb + (size_t)(jt * 64 + rr) * NDH + c4;
            float4 v0 = *(const float4*)(src + 0);
            float4 v1 = *(const float4*)(src + 4);
            float4 v2 = *(const float4*)(src + 8);
            float4 v3 = *(const float4*)(src + 12);
            const float tmp[16] = {v0.x,v0.y,v0.z,v0.w, v1.x,v1.y,v1.z,v1.w,
                                   v2.x,v2.y,v2.z,v2.w, v3.x,v3.y,v3.z,v3.w};
#pragma unroll
            for (int u = 0; u < 16; ++u) Kst[c4 + u][rr] = tmp[u];
            // V row-major, coalesced
            const float* vsrc = Vb + (size_t)(jt * 64 + rr) * NDH + c4;
            *(float4*)&Vs[rr][c4 + 0]  = *(const float4*)(vsrc + 0);
            *(float4*)&Vs[rr][c4 + 4]  = *(const float4*)(vsrc + 4);
            *(float4*)&Vs[rr][c4 + 8]  = *(const float4*)(vsrc + 8);
            *(float4*)&Vs[rr][c4 + 12] = *(const float4*)(vsrc + 12);
            if (t < 64) rzs[t] = 1.0f / Z[jt * 64 + t];
        }
        __syncthreads();

        // S tile: rows i (ty), cols j (tx)
        float s[4][4] = {};
#pragma unroll 8
        for (int dd = 0; dd < 64; ++dd) {
            const float4 qa4 = *(const float4*)&Qst[dd][ty * 4];
            const float4 kb4 = *(const float4*)&Kst[dd][tx * 4];
            const float qa[4] = {qa4.x, qa4.y, qa4.z, qa4.w};
            const float kb[4] = {kb4.x, kb4.y, kb4.z, kb4.w};
#pragma unroll
            for (int r = 0; r < 4; ++r)
#pragma unroll
                for (int c = 0; c < 4; ++c)
                    s[r][c] = fmaf(qa[r], kb[c], s[r][c]);
        }
        const float rz[4] = {rzs[tx * 4], rzs[tx * 4 + 1], rzs[tx * 4 + 2], rzs[tx * 4 + 3]};
#pragma unroll
        for (int r = 0; r < 4; ++r)
#pragma unroll
            for (int c = 0; c < 4; ++c)
                Pst[tx * 4 + c][ty * 4 + r] = __expf(s[r][c] * SCALE) * rz[c];
        __syncthreads();

        // acc += P @ V : acc[r][c] over i rows (ty), k cols (tx)
#pragma unroll 8
        for (int jj = 0; jj < 64; ++jj) {
            const float4 pa4 = *(const float4*)&Pst[jj][ty * 4];
            const float4 vb4 = *(const float4*)&Vs[jj][tx * 4];
            const float pa[4] = {pa4.x, pa4.y, pa4.z, pa4.w};
            const float vb[4] = {vb4.x, vb4.y, vb4.z, vb4.w};
#pragma unroll
            for (int r = 0; r < 4; ++r)
#pragma unroll
                for (int c = 0; c < 4; ++c)
                    acc[r][c] = fmaf(pa[r], vb[c], acc[r][c]);
        }
    }

#pragma unroll
    for (int r = 0; r < 4; ++r) {
        const int l = it * 64 + ty * 4 + r;
        float4 o;
        o.x = acc[r][0]; o.y = acc[r][1]; o.z = acc[r][2]; o.w = acc[r][3];
        *(float4*)&AO[((size_t)(b * NL + l)) * ND + h * 64 + tx * 4] = o;
    }
}

// ---------------------------------------------------------------------------
// Kernel 4: Y = AO @ WO^T + bO   (WO is [out,in] torch layout: y[.,e] = sum_d a[.,d]*WO[e,d])
// ---------------------------------------------------------------------------
__global__ __launch_bounds__(256) void k_oproj(
    const float* __restrict__ AO, const float* __restrict__ WO,
    const float* __restrict__ bO, float* __restrict__ y)
{
    __shared__ float As[64][36];    // AO tile [64 m][32 d]
    __shared__ float Bst[32][68];   // WO^T tile [32 d][64 e]

    const int mt = blockIdx.x;   // 0..63
    const int nt = blockIdx.y;   // 0..15

    const int t  = threadIdx.x;
    const int tx = t & 15;
    const int ty = t >> 4;

    const int ar = t >> 2;          // 0..63
    const int ac = (t & 3) * 8;
    const float* asrc = AO + (size_t)(mt * 64 + ar) * ND + ac;
    const int er = t >> 2;          // 0..63 (e row)
    const int dc = (t & 3) * 8;     // 0..24
    const float* wsrc = WO + (size_t)(nt * 64 + er) * ND + dc;

    float acc[4][4] = {};

    for (int k0 = 0; k0 < ND; k0 += 32) {
        __syncthreads();
        float4 a0 = *(const float4*)(asrc + k0);
        float4 a1 = *(const float4*)(asrc + k0 + 4);
        float4 w0 = *(const float4*)(wsrc + k0);
        float4 w1 = *(const float4*)(wsrc + k0 + 4);
        *(float4*)&As[ar][ac]     = a0;
        *(float4*)&As[ar][ac + 4] = a1;
        const float wt[8] = {w0.x,w0.y,w0.z,w0.w, w1.x,w1.y,w1.z,w1.w};
#pragma unroll
        for (int u = 0; u < 8; ++u) Bst[dc + u][er] = wt[u];
        __syncthreads();

#pragma unroll
        for (int kk = 0; kk < 32; ++kk) {
            float a[4];
#pragma unroll
            for (int r = 0; r < 4; ++r) a[r] = As[ty * 4 + r][kk];
            const float4 b4 = *(const float4*)&Bst[kk][tx * 4];
            const float bb[4] = {b4.x, b4.y, b4.z, b4.w};
#pragma unroll
            for (int r = 0; r < 4; ++r)
#pragma unroll
                for (int c = 0; c < 4; ++c)
                    acc[r][c] = fmaf(a[r], bb[c], acc[r][c]);
        }
    }

    const float4 bo4 = *(const float4*)(bO + nt * 64 + tx * 4);
    const float bo[4] = {bo4.x, bo4.y, bo4.z, bo4.w};
#pragma unroll
    for (int r = 0; r < 4; ++r) {
        const int m = mt * 64 + ty * 4 + r;
        float4 o;
        o.x = acc[r][0] + bo[0];
        o.y = acc[r][1] + bo[1];
        o.z = acc[r][2] + bo[2];
        o.w = acc[r][3] + bo[3];
        *(float4*)&y[(size_t)m * ND + nt * 64 + tx * 4] = o;
    }
}

// ---------------------------------------------------------------------------
extern "C" void kernel_launch(void* const* d_in, const int* in_sizes, int n_in,
                              void* d_out, int out_size, void* d_ws, size_t ws_size,
                              hipStream_t stream)
{
    const float* x  = (const float*)d_in[0];
    const float* Wq = (const float*)d_in[1];
    const float* bq = (const float*)d_in[2];
    const float* Wk = (const float*)d_in[3];
    const float* bk = (const float*)d_in[4];
    const float* Wv = (const float*)d_in[5];
    const float* bv = (const float*)d_in[6];
    const float* WO = (const float*)d_in[7];
    const float* bO = (const float*)d_in[8];
    float* y  = (float*)d_out;
    float* ws = (float*)d_ws;

    float* Zout = ws + 3 * (size_t)QKV_ELEMS;                        // [B*H*L]
    float* AO   = ws + 3 * (size_t)QKV_ELEMS + (size_t)NB * NH * NL; // [B*L*D]

    hipLaunchKernelGGL(k_qkv,    dim3(64, 48), dim3(256), 0, stream,
                       x, Wq, bq, Wk, bk, Wv, bv, ws);
    hipLaunchKernelGGL(k_colsum, dim3(32, 32), dim3(256), 0, stream, ws, Zout);
    hipLaunchKernelGGL(k_av,     dim3(32, 32), dim3(256), 0, stream, ws, AO);
    hipLaunchKernelGGL(k_oproj,  dim3(64, 16), dim3(256), 0, stream, AO, WO, bO, y);
}

// Round 3
// 285.048 us; speedup vs baseline: 4.6357x; 4.6357x over previous
//
#include <hip/hip_runtime.h>
#include <math.h>

#define NB 2
#define NL 2048
#define ND 1024
#define NH 16
#define NDH 64
static constexpr float SCALE = 0.125f;   // 1/sqrt(64)

typedef short          bhalf8 __attribute__((ext_vector_type(8)));   // 8 bf16 (4 VGPR)
typedef unsigned short ush8   __attribute__((ext_vector_type(8)));
typedef unsigned short ush4   __attribute__((ext_vector_type(4)));
typedef float          f32x4  __attribute__((ext_vector_type(4)));

#define MFMA_BF16(a, b, c) __builtin_amdgcn_mfma_f32_16x16x32_bf16(a, b, c, 0, 0, 0)

__device__ __forceinline__ unsigned short f2bf(float f) {
    unsigned u = __float_as_uint(f);
    u += 0x7FFF + ((u >> 16) & 1);           // round-to-nearest-even
    return (unsigned short)(u >> 16);
}
__device__ __forceinline__ float bf2f(unsigned short s) {
    return __uint_as_float((unsigned)s << 16);
}

// ---------------------------------------------------------------------------
// Convert 1: elementwise fp32->bf16 for x (4M elems) then WO (1M elems).
// ---------------------------------------------------------------------------
__global__ __launch_bounds__(256) void k_cvt(
    const float* __restrict__ x, const float* __restrict__ WO,
    unsigned short* __restrict__ xb, unsigned short* __restrict__ wob)
{
    size_t u = (size_t)blockIdx.x * 256 + threadIdx.x;   // one 8-elem unit each
    const float* src; unsigned short* dst; size_t off;
    if (u < 524288) { src = x;  dst = xb;  off = u * 8; }
    else            { src = WO; dst = wob; off = (u - 524288) * 8; }
    float4 a = *(const float4*)(src + off);
    float4 b = *(const float4*)(src + off + 4);
    ush8 o;
    o[0] = f2bf(a.x); o[1] = f2bf(a.y); o[2] = f2bf(a.z); o[3] = f2bf(a.w);
    o[4] = f2bf(b.x); o[5] = f2bf(b.y); o[6] = f2bf(b.z); o[7] = f2bf(b.w);
    *(ush8*)(dst + off) = o;
}

// ---------------------------------------------------------------------------
// Convert 2: Wq/Wk/Wv [h][1024 d][64 dh] fp32 -> Wtb [qkv][h][64 dh][1024 d] bf16
// (transposed so the GEMM B-operand fragment reads are d-contiguous)
// ---------------------------------------------------------------------------
__global__ __launch_bounds__(256) void k_cvt_wt(
    const float* __restrict__ Wq, const float* __restrict__ Wk,
    const float* __restrict__ Wv, unsigned short* __restrict__ Wtb)
{
    __shared__ unsigned short T[64][72];
    const int d0  = blockIdx.x * 64;       // d chunk
    const int qkv = blockIdx.y >> 4;
    const int h   = blockIdx.y & 15;
    const float* W = (qkv == 0 ? Wq : (qkv == 1 ? Wk : Wv)) + (size_t)h * (ND * NDH);
    const int t = threadIdx.x;
#pragma unroll
    for (int p = 0; p < 4; ++p) {
        int u  = t + p * 256;
        int dr = u >> 4;             // 0..63 (d row)
        int c4 = (u & 15) * 4;       // dh
        float4 v = *(const float4*)(W + (size_t)(d0 + dr) * NDH + c4);
        T[c4 + 0][dr] = f2bf(v.x);
        T[c4 + 1][dr] = f2bf(v.y);
        T[c4 + 2][dr] = f2bf(v.z);
        T[c4 + 3][dr] = f2bf(v.w);
    }
    __syncthreads();
    unsigned short* outp = Wtb + (size_t)(qkv * NH + h) * NDH * ND;
#pragma unroll
    for (int p = 0; p < 2; ++p) {
        int u  = t + p * 256;
        int dh = u >> 3;
        int sg = (u & 7) * 8;
        *(ush8*)(outp + (size_t)dh * ND + d0 + sg) = *(ush8*)&T[dh][sg];
    }
}

// ---------------------------------------------------------------------------
// QKV projection via MFMA. Tile 128(m) x 64(dh), K-step 32. 4 waves, 32 m each.
// Q,K -> [bh][L][64] bf16 row-major.  V -> Vt [bh][64][L] bf16 (transposed).
// ---------------------------------------------------------------------------
__global__ __launch_bounds__(256) void k_qkv_mfma(
    const unsigned short* __restrict__ xb, const unsigned short* __restrict__ Wtb,
    const float* __restrict__ bq, const float* __restrict__ bk,
    const float* __restrict__ bv,
    unsigned short* __restrict__ Qb, unsigned short* __restrict__ Kb,
    unsigned short* __restrict__ Vtb)
{
    __shared__ unsigned short As[128][40];   // x tile [m][k], pad->80B stride
    __shared__ unsigned short Bs[64][40];    // Wt tile [dh][k]

    const int mt  = blockIdx.x;        // 0..31
    const int qkv = blockIdx.y >> 4;
    const int h   = blockIdx.y & 15;
    const int t = threadIdx.x, w = t >> 6, lane = t & 63;
    const int lr = lane & 15, lg = lane >> 4;
    const int wm = w * 32;

    const unsigned short* wt = Wtb + (size_t)(qkv * NH + h) * NDH * ND;
    const float* bias = (qkv == 0 ? bq : (qkv == 1 ? bk : bv)) + h * NDH;

    f32x4 acc[2][4] = {};

    for (int k0 = 0; k0 < ND; k0 += 32) {
        __syncthreads();
#pragma unroll
        for (int p = 0; p < 2; ++p) {            // A: 128x32 = 512 16B-units
            int u = t + p * 256;
            int r = u >> 2, sg = (u & 3) * 8;
            *(ush8*)&As[r][sg] = *(const ush8*)(xb + (size_t)(mt * 128 + r) * ND + k0 + sg);
        }
        {                                        // B: 64x32 = 256 units
            int r = t >> 2, sg = (t & 3) * 8;
            *(ush8*)&Bs[r][sg] = *(const ush8*)(wt + (size_t)r * ND + k0 + sg);
        }
        __syncthreads();

        bhalf8 a0 = *(const bhalf8*)&As[wm + lr][lg * 8];
        bhalf8 a1 = *(const bhalf8*)&As[wm + 16 + lr][lg * 8];
#pragma unroll
        for (int nf = 0; nf < 4; ++nf) {
            bhalf8 b = *(const bhalf8*)&Bs[nf * 16 + lr][lg * 8];
            acc[0][nf] = MFMA_BF16(a0, b, acc[0][nf]);
            acc[1][nf] = MFMA_BF16(a1, b, acc[1][nf]);
        }
    }

#pragma unroll
    for (int mf = 0; mf < 2; ++mf) {
#pragma unroll
        for (int nf = 0; nf < 4; ++nf) {
            const int col = nf * 16 + lr;
            const float bi = bias[col];
            if (qkv < 2) {
                unsigned short* outp = (qkv == 0 ? Qb : Kb);
#pragma unroll
                for (int r = 0; r < 4; ++r) {
                    int m = mt * 128 + wm + mf * 16 + lg * 4 + r;
                    int b = m >> 11, l = m & (NL - 1);
                    outp[((size_t)(b * NH + h) * NL + l) * NDH + col] =
                        f2bf(acc[mf][nf][r] + bi);
                }
            } else {
                int m0 = mt * 128 + wm + mf * 16 + lg * 4;   // 4 consecutive l
                int b = m0 >> 11, l0 = m0 & (NL - 1);
                ush4 pk;
#pragma unroll
                for (int r = 0; r < 4; ++r) pk[r] = f2bf(acc[mf][nf][r] + bi);
                *(ush4*)(Vtb + ((size_t)(b * NH + h) * NDH + col) * NL + l0) = pk;
            }
        }
    }
}

// ---------------------------------------------------------------------------
// Column stats: Zrcp[bh][j] = 1 / sum_i exp(SCALE * Q_i.K_j)
// S^T = K.Q^T via MFMA (A=K rows j, B=Q rows i). Block: (bh, j-tile 128).
// Wave owns 32 j; every wave streams all i.
// ---------------------------------------------------------------------------
__global__ __launch_bounds__(256) void k_colsum_mfma(
    const unsigned short* __restrict__ Qb, const unsigned short* __restrict__ Kb,
    float* __restrict__ Zr)
{
    __shared__ unsigned short Ks[128][72];
    __shared__ unsigned short Qs[64][72];

    const int jt = blockIdx.x;    // 0..15
    const int bh = blockIdx.y;    // 0..31
    const unsigned short* Qp = Qb + (size_t)bh * NL * NDH;
    const unsigned short* Kp = Kb + (size_t)bh * NL * NDH;
    const int t = threadIdx.x, w = t >> 6, lane = t & 63;
    const int lr = lane & 15, lg = lane >> 4;
    const int wj = w * 32;

#pragma unroll
    for (int p = 0; p < 4; ++p) {          // K tile 128x64, staged once
        int u = t + p * 256;
        int r = u >> 3, sg = (u & 7) * 8;
        *(ush8*)&Ks[r][sg] = *(const ush8*)(Kp + (size_t)(jt * 128 + r) * NDH + sg);
    }

    float zacc[2][4] = {};

    for (int it = 0; it < 32; ++it) {
        __syncthreads();
#pragma unroll
        for (int p = 0; p < 2; ++p) {      // Q tile 64x64
            int u = t + p * 256;
            int r = u >> 3, sg = (u & 7) * 8;
            *(ush8*)&Qs[r][sg] = *(const ush8*)(Qp + (size_t)(it * 64 + r) * NDH + sg);
        }
        __syncthreads();

        bhalf8 ka[2][2], qv[4][2];
#pragma unroll
        for (int jf = 0; jf < 2; ++jf)
#pragma unroll
            for (int ks = 0; ks < 2; ++ks)
                ka[jf][ks] = *(const bhalf8*)&Ks[wj + jf * 16 + lr][ks * 32 + lg * 8];
#pragma unroll
        for (int ii = 0; ii < 4; ++ii)
#pragma unroll
            for (int ks = 0; ks < 2; ++ks)
                qv[ii][ks] = *(const bhalf8*)&Qs[ii * 16 + lr][ks * 32 + lg * 8];

#pragma unroll
        for (int jf = 0; jf < 2; ++jf)
#pragma unroll
            for (int ii = 0; ii < 4; ++ii) {
                f32x4 s = {};
                s = MFMA_BF16(ka[jf][0], qv[ii][0], s);
                s = MFMA_BF16(ka[jf][1], qv[ii][1], s);
#pragma unroll
                for (int r = 0; r < 4; ++r)
                    zacc[jf][r] += __expf(s[r] * SCALE);
            }
    }

    // reduce over the 16 lanes holding different i (lane low bits)
#pragma unroll
    for (int jf = 0; jf < 2; ++jf)
#pragma unroll
        for (int r = 0; r < 4; ++r) {
            float v = zacc[jf][r];
            v += __shfl_xor(v, 1);
            v += __shfl_xor(v, 2);
            v += __shfl_xor(v, 4);
            v += __shfl_xor(v, 8);
            zacc[jf][r] = v;
        }
    if (lr == 0) {
#pragma unroll
        for (int jf = 0; jf < 2; ++jf)
#pragma unroll
            for (int r = 0; r < 4; ++r)
                Zr[(size_t)bh * NL + jt * 128 + wj + jf * 16 + lg * 4 + r] =
                    1.0f / zacc[jf][r];
    }
}

// ---------------------------------------------------------------------------
// O[i][dh] = sum_j exp(SCALE*S_ij) * (V[j][dh] / Z_j).  Block: (bh, i-tile 128).
// Streams j-tiles of 64: recompute S^T via MFMA, exp -> P (LDS, bf16),
// then PV MFMA with V pre-scaled by 1/Z at staging. Output head-concat bf16.
// ---------------------------------------------------------------------------
__global__ __launch_bounds__(256) void k_av_mfma(
    const unsigned short* __restrict__ Qb, const unsigned short* __restrict__ Kb,
    const unsigned short* __restrict__ Vtb, const float* __restrict__ Zr,
    unsigned short* __restrict__ AOb)
{
    __shared__ unsigned short Qs[128][72];
    __shared__ unsigned short Ks[64][72];
    __shared__ unsigned short Vts[64][72];   // [dh][j], scaled by 1/Z_j
    __shared__ unsigned short Ps[128][72];   // [i][j] bf16

    const int it = blockIdx.x;   // 0..15
    const int bh = blockIdx.y;   // 0..31
    const int b = bh >> 4, h = bh & 15;
    const unsigned short* Qp = Qb  + (size_t)bh * NL * NDH;
    const unsigned short* Kp = Kb  + (size_t)bh * NL * NDH;
    const unsigned short* Vp = Vtb + (size_t)bh * NDH * NL;
    const float* Zp = Zr + (size_t)bh * NL;

    const int t = threadIdx.x, w = t >> 6, lane = t & 63;
    const int lr = lane & 15, lg = lane >> 4;
    const int wi = w * 32;

#pragma unroll
    for (int p = 0; p < 4; ++p) {            // Q tile 128x64, staged once
        int u = t + p * 256;
        int r = u >> 3, sg = (u & 7) * 8;
        *(ush8*)&Qs[r][sg] = *(const ush8*)(Qp + (size_t)(it * 128 + r) * NDH + sg);
    }

    f32x4 oacc[2][4] = {};

    for (int jt = 0; jt < 32; ++jt) {
        __syncthreads();     // prev iter's Ks/Vts/Ps reads complete (iter0: nothing)
#pragma unroll
        for (int p = 0; p < 2; ++p) {        // K tile 64x64
            int u = t + p * 256;
            int r = u >> 3, sg = (u & 7) * 8;
            *(ush8*)&Ks[r][sg] = *(const ush8*)(Kp + (size_t)(jt * 64 + r) * NDH + sg);
        }
#pragma unroll
        for (int p = 0; p < 2; ++p) {        // Vt tile [64 dh][64 j] * (1/Z_j)
            int u  = t + p * 256;
            int dh = u >> 3, sg = (u & 7) * 8;
            ush8 v = *(const ush8*)(Vp + (size_t)dh * NL + jt * 64 + sg);
            float4 z0 = *(const float4*)(Zp + jt * 64 + sg);
            float4 z1 = *(const float4*)(Zp + jt * 64 + sg + 4);
            ush8 o;
            o[0] = f2bf(bf2f(v[0]) * z0.x); o[1] = f2bf(bf2f(v[1]) * z0.y);
            o[2] = f2bf(bf2f(v[2]) * z0.z); o[3] = f2bf(bf2f(v[3]) * z0.w);
            o[4] = f2bf(bf2f(v[4]) * z1.x); o[5] = f2bf(bf2f(v[5]) * z1.y);
            o[6] = f2bf(bf2f(v[6]) * z1.z); o[7] = f2bf(bf2f(v[7]) * z1.w);
            *(ush8*)&Vts[dh][sg] = o;
        }
        __syncthreads();

        // S phase: S^T fragments [4 jf (all 64 j)][2 ii (own 32 i)]
        bhalf8 ka[4][2], qv[2][2];
#pragma unroll
        for (int jf = 0; jf < 4; ++jf)
#pragma unroll
            for (int ks = 0; ks < 2; ++ks)
                ka[jf][ks] = *(const bhalf8*)&Ks[jf * 16 + lr][ks * 32 + lg * 8];
#pragma unroll
        for (int ii = 0; ii < 2; ++ii)
#pragma unroll
            for (int ks = 0; ks < 2; ++ks)
                qv[ii][ks] = *(const bhalf8*)&Qs[wi + ii * 16 + lr][ks * 32 + lg * 8];

#pragma unroll
        for (int ii = 0; ii < 2; ++ii)
#pragma unroll
            for (int jf = 0; jf < 4; ++jf) {
                f32x4 s = {};
                s = MFMA_BF16(ka[jf][0], qv[ii][0], s);
                s = MFMA_BF16(ka[jf][1], qv[ii][1], s);
                ush4 pk;
#pragma unroll
                for (int r = 0; r < 4; ++r)
                    pk[r] = f2bf(__expf(s[r] * SCALE));
                // S^T: row j = jf*16+lg*4+r (4 consecutive), col i = wi+ii*16+lr
                *(ush4*)&Ps[wi + ii * 16 + lr][jf * 16 + lg * 4] = pk;
            }
        __syncthreads();

        // PV phase: A = P [i][j], B = Vts (= V^T scaled) -> oacc[ii][nf]
        bhalf8 pa[2][2], vb[4][2];
#pragma unroll
        for (int ii = 0; ii < 2; ++ii)
#pragma unroll
            for (int ks = 0; ks < 2; ++ks)
                pa[ii][ks] = *(const bhalf8*)&Ps[wi + ii * 16 + lr][ks * 32 + lg * 8];
#pragma unroll
        for (int nf = 0; nf < 4; ++nf)
#pragma unroll
            for (int ks = 0; ks < 2; ++ks)
                vb[nf][ks] = *(const bhalf8*)&Vts[nf * 16 + lr][ks * 32 + lg * 8];
#pragma unroll
        for (int ii = 0; ii < 2; ++ii)
#pragma unroll
            for (int nf = 0; nf < 4; ++nf) {
                oacc[ii][nf] = MFMA_BF16(pa[ii][0], vb[nf][0], oacc[ii][nf]);
                oacc[ii][nf] = MFMA_BF16(pa[ii][1], vb[nf][1], oacc[ii][nf]);
            }
    }

    // epilogue: AO[b, l, h*64+dh] bf16
#pragma unroll
    for (int ii = 0; ii < 2; ++ii)
#pragma unroll
        for (int nf = 0; nf < 4; ++nf)
#pragma unroll
            for (int r = 0; r < 4; ++r) {
                int l   = it * 128 + wi + ii * 16 + lg * 4 + r;
                int col = h * NDH + nf * 16 + lr;
                AOb[((size_t)(b * NL + l)) * ND + col] = f2bf(oacc[ii][nf][r]);
            }
}

// ---------------------------------------------------------------------------
// Output projection: y[m][e] = sum_d AO[m][d]*WO[e][d] + bO[e].  fp32 out.
// Tile 128x128, 4 waves as 2x2 of 64x64.
// ---------------------------------------------------------------------------
__global__ __launch_bounds__(256) void k_oproj_mfma(
    const unsigned short* __restrict__ AOb, const unsigned short* __restrict__ WOb,
    const float* __restrict__ bO, float* __restrict__ y)
{
    __shared__ unsigned short As[128][40];
    __shared__ unsigned short Bs[128][40];   // WO rows e

    const int mt = blockIdx.x;   // 0..31
    const int nt = blockIdx.y;   // 0..7
    const int t = threadIdx.x, w = t >> 6, lane = t & 63;
    const int lr = lane & 15, lg = lane >> 4;
    const int wm = (w >> 1) * 64, wn = (w & 1) * 64;

    f32x4 acc[4][4] = {};

    for (int k0 = 0; k0 < ND; k0 += 32) {
        __syncthreads();
#pragma unroll
        for (int p = 0; p < 2; ++p) {
            int u = t + p * 256;
            int r = u >> 2, sg = (u & 3) * 8;
            *(ush8*)&As[r][sg] = *(const ush8*)(AOb + (size_t)(mt * 128 + r) * ND + k0 + sg);
            *(ush8*)&Bs[r][sg] = *(const ush8*)(WOb + (size_t)(nt * 128 + r) * ND + k0 + sg);
        }
        __syncthreads();

        bhalf8 av[4], bv[4];
#pragma unroll
        for (int mf = 0; mf < 4; ++mf)
            av[mf] = *(const bhalf8*)&As[wm + mf * 16 + lr][lg * 8];
#pragma unroll
        for (int nf = 0; nf < 4; ++nf)
            bv[nf] = *(const bhalf8*)&Bs[wn + nf * 16 + lr][lg * 8];
#pragma unroll
        for (int mf = 0; mf < 4; ++mf)
#pragma unroll
            for (int nf = 0; nf < 4; ++nf)
                acc[mf][nf] = MFMA_BF16(av[mf], bv[nf], acc[mf][nf]);
    }

#pragma unroll
    for (int mf = 0; mf < 4; ++mf)
#pragma unroll
        for (int nf = 0; nf < 4; ++nf) {
            int e = nt * 128 + wn + nf * 16 + lr;
            float bo = bO[e];
#pragma unroll
            for (int r = 0; r < 4; ++r) {
                int m = mt * 128 + wm + mf * 16 + lg * 4 + r;
                y[(size_t)m * ND + e] = acc[mf][nf][r] + bo;
            }
        }
}

// ---------------------------------------------------------------------------
extern "C" void kernel_launch(void* const* d_in, const int* in_sizes, int n_in,
                              void* d_out, int out_size, void* d_ws, size_t ws_size,
                              hipStream_t stream)
{
    const float* x  = (const float*)d_in[0];
    const float* Wq = (const float*)d_in[1];
    const float* bq = (const float*)d_in[2];
    const float* Wk = (const float*)d_in[3];
    const float* bk = (const float*)d_in[4];
    const float* Wv = (const float*)d_in[5];
    const float* bv = (const float*)d_in[6];
    const float* WO = (const float*)d_in[7];
    const float* bO = (const float*)d_in[8];
    float* y = (float*)d_out;

    unsigned short* xb  = (unsigned short*)d_ws;     // 4,194,304 elems (8 MB)
    unsigned short* Wtb = xb  + 4194304;             // 3,145,728      (6 MB)
    unsigned short* WOb = Wtb + 3145728;             // 1,048,576      (2 MB)
    unsigned short* Qb  = WOb + 1048576;             // 4,194,304      (8 MB)
    unsigned short* Kb  = Qb  + 4194304;             // 4,194,304      (8 MB)
    unsigned short* Vtb = Kb  + 4194304;             // 4,194,304      (8 MB)
    float*          Zr  = (float*)(Vtb + 4194304);   // 65,536 f32     (256 KB)
    unsigned short* AOb = (unsigned short*)(Zr + 65536); // 4,194,304  (8 MB)

    hipLaunchKernelGGL(k_cvt,         dim3(2560),    dim3(256), 0, stream, x, WO, xb, WOb);
    hipLaunchKernelGGL(k_cvt_wt,      dim3(16, 48),  dim3(256), 0, stream, Wq, Wk, Wv, Wtb);
    hipLaunchKernelGGL(k_qkv_mfma,    dim3(32, 48),  dim3(256), 0, stream,
                       xb, Wtb, bq, bk, bv, Qb, Kb, Vtb);
    hipLaunchKernelGGL(k_colsum_mfma, dim3(16, 32),  dim3(256), 0, stream, Qb, Kb, Zr);
    hipLaunchKernelGGL(k_av_mfma,     dim3(16, 32),  dim3(256), 0, stream,
                       Qb, Kb, Vtb, Zr, AOb);
    hipLaunchKernelGGL(k_oproj_mfma,  dim3(32, 8),   dim3(256), 0, stream, AOb, WOb, bO, y);
}

// Round 4
// 231.828 us; speedup vs baseline: 5.6998x; 1.2296x over previous
//
#include <hip/hip_runtime.h>
#include <math.h>

#define NB 2
#define NL 2048
#define ND 1024
#define NH 16
#define NDH 64
static constexpr float SCALE = 0.125f;   // 1/sqrt(64)

typedef short          bhalf8 __attribute__((ext_vector_type(8)));   // 8 bf16 (4 VGPR)
typedef unsigned short ush8   __attribute__((ext_vector_type(8)));
typedef unsigned short ush4   __attribute__((ext_vector_type(4)));
typedef float          f32x4  __attribute__((ext_vector_type(4)));

#define MFMA_BF16(a, b, c) __builtin_amdgcn_mfma_f32_16x16x32_bf16(a, b, c, 0, 0, 0)

__device__ __forceinline__ unsigned short f2bf(float f) {
    unsigned u = __float_as_uint(f);
    u += 0x7FFF + ((u >> 16) & 1);           // RNE
    return (unsigned short)(u >> 16);
}
__device__ __forceinline__ float bf2f(unsigned short s) {
    return __uint_as_float((unsigned)s << 16);
}
// pack two floats to two bf16 (round-half-up) in ONE dword: [15:0]=lo, [31:16]=hi
__device__ __forceinline__ unsigned pack_bf16(float lo, float hi) {
    unsigned a = __float_as_uint(lo) + 0x8000u;
    unsigned b = __float_as_uint(hi) + 0x8000u;
    return __builtin_amdgcn_perm(b, a, 0x07060302u);
}

// ---------------------------------------------------------------------------
// Convert 1: fp32->bf16 for x (4M elems) then WO (1M elems).
// ---------------------------------------------------------------------------
__global__ __launch_bounds__(256) void k_cvt(
    const float* __restrict__ x, const float* __restrict__ WO,
    unsigned short* __restrict__ xb, unsigned short* __restrict__ wob)
{
    size_t u = (size_t)blockIdx.x * 256 + threadIdx.x;
    const float* src; unsigned short* dst; size_t off;
    if (u < 524288) { src = x;  dst = xb;  off = u * 8; }
    else            { src = WO; dst = wob; off = (u - 524288) * 8; }
    float4 a = *(const float4*)(src + off);
    float4 b = *(const float4*)(src + off + 4);
    uint4 o;
    o.x = pack_bf16(a.x, a.y); o.y = pack_bf16(a.z, a.w);
    o.z = pack_bf16(b.x, b.y); o.w = pack_bf16(b.z, b.w);
    *(uint4*)(dst + off) = o;
}

// ---------------------------------------------------------------------------
// Convert 2: Wq/Wk/Wv [h][1024 d][64 dh] fp32 -> Wtb [qkv][h][64 dh][1024 d] bf16
// (= one stacked [3072 n][1024 d] B^T matrix, n = qkv*1024 + h*64 + dh)
// ---------------------------------------------------------------------------
__global__ __launch_bounds__(256) void k_cvt_wt(
    const float* __restrict__ Wq, const float* __restrict__ Wk,
    const float* __restrict__ Wv, unsigned short* __restrict__ Wtb)
{
    __shared__ unsigned short T[64][72];
    const int d0  = blockIdx.x * 64;
    const int qkv = blockIdx.y >> 4;
    const int h   = blockIdx.y & 15;
    const float* W = (qkv == 0 ? Wq : (qkv == 1 ? Wk : Wv)) + (size_t)h * (ND * NDH);
    const int t = threadIdx.x;
#pragma unroll
    for (int p = 0; p < 4; ++p) {
        int u  = t + p * 256;
        int dr = u >> 4;
        int c4 = (u & 15) * 4;
        float4 v = *(const float4*)(W + (size_t)(d0 + dr) * NDH + c4);
        T[c4 + 0][dr] = f2bf(v.x);
        T[c4 + 1][dr] = f2bf(v.y);
        T[c4 + 2][dr] = f2bf(v.z);
        T[c4 + 3][dr] = f2bf(v.w);
    }
    __syncthreads();
    unsigned short* outp = Wtb + (size_t)(qkv * NH + h) * NDH * ND;
#pragma unroll
    for (int p = 0; p < 2; ++p) {
        int u  = t + p * 256;
        int dh = u >> 3;
        int sg = (u & 7) * 8;
        *(ush8*)(outp + (size_t)dh * ND + d0 + sg) = *(ush8*)&T[dh][sg];
    }
}

// ---------------------------------------------------------------------------
// QKV projection as ONE GEMM: out[m][n] = sum_d xb[m][d]*Wtb[n][d],
// m=4096, n=3072, 128x128 tile, BK=64, 4 waves (2x2 of 64x64).
// Epilogue: LDS transpose -> coalesced writes. Q,K row-major [bh][L][64];
// V transposed [bh][64][L].
// ---------------------------------------------------------------------------
__global__ __launch_bounds__(256, 2) void k_qkv_mfma(
    const unsigned short* __restrict__ xb, const unsigned short* __restrict__ Wtb,
    const float* __restrict__ bq, const float* __restrict__ bk,
    const float* __restrict__ bv,
    unsigned short* __restrict__ Qb, unsigned short* __restrict__ Kb,
    unsigned short* __restrict__ Vtb)
{
    __shared__ unsigned short LB[2 * 128 * 64];   // As|Bs, reused as TS[128][128]
    unsigned short* As = LB;
    unsigned short* Bs = LB + 128 * 64;

    const int mt = blockIdx.x;   // 0..31
    const int nt = blockIdx.y;   // 0..23
    const int qkv = nt >> 3;
    const int t = threadIdx.x, w = t >> 6, lane = t & 63;
    const int lr = lane & 15, lg = lane >> 4;
    const int wm = (w >> 1) * 64, wn = (w & 1) * 64;
    const int swz = (lr & 7) << 3;

    f32x4 acc[4][4] = {};

    for (int k0 = 0; k0 < ND; k0 += 64) {
        __syncthreads();
#pragma unroll
        for (int p = 0; p < 4; ++p) {
            int u = t + p * 256;
            int r = u >> 3, sg = (u & 7) * 8;
            int sc = sg ^ ((r & 7) << 3);
            *(ush8*)&As[r * 64 + sc] = *(const ush8*)(xb  + (size_t)(mt * 128 + r) * ND + k0 + sg);
            *(ush8*)&Bs[r * 64 + sc] = *(const ush8*)(Wtb + (size_t)(nt * 128 + r) * ND + k0 + sg);
        }
        __syncthreads();

        bhalf8 av[4][2], bw[4][2];
#pragma unroll
        for (int f = 0; f < 4; ++f)
#pragma unroll
            for (int ks = 0; ks < 2; ++ks) {
                int c = (ks * 32 + lg * 8) ^ swz;
                av[f][ks] = *(const bhalf8*)&As[(wm + f * 16 + lr) * 64 + c];
                bw[f][ks] = *(const bhalf8*)&Bs[(wn + f * 16 + lr) * 64 + c];
            }
#pragma unroll
        for (int mf = 0; mf < 4; ++mf)
#pragma unroll
            for (int nf = 0; nf < 4; ++nf) {
                acc[mf][nf] = MFMA_BF16(av[mf][0], bw[nf][0], acc[mf][nf]);
                acc[mf][nf] = MFMA_BF16(av[mf][1], bw[nf][1], acc[mf][nf]);
            }
    }

    const float* bias = (qkv == 0 ? bq : (qkv == 1 ? bk : bv));
    const int nb = (nt & 7) * 128;
    float bi[4];
#pragma unroll
    for (int nf = 0; nf < 4; ++nf) bi[nf] = bias[nb + wn + nf * 16 + lr];

    __syncthreads();                    // done with As/Bs
    unsigned short* TS = LB;            // [128][128], xor-swizzled

    if (qkv < 2) {
        // TS[m][n]: stage bf16, then write coalesced rows (l-major, dh contig)
#pragma unroll
        for (int mf = 0; mf < 4; ++mf)
#pragma unroll
            for (int nf = 0; nf < 4; ++nf)
#pragma unroll
                for (int r = 0; r < 4; ++r) {
                    int m = wm + mf * 16 + lg * 4 + r;
                    int n = (wn + nf * 16 + lr) ^ ((m & 7) << 3);
                    TS[m * 128 + n] = f2bf(acc[mf][nf][r] + bi[nf]);
                }
        __syncthreads();
        unsigned short* outp = (qkv == 0 ? Qb : Kb);
#pragma unroll
        for (int p = 0; p < 8; ++p) {
            int u = t + p * 256;
            int r = u >> 4, sg = (u & 15) * 8;
            ush8 v = *(const ush8*)&TS[r * 128 + (sg ^ ((r & 7) << 3))];
            int m = mt * 128 + r;
            int b = m >> 11, l = m & (NL - 1);
            int n = nb + sg;
            int h = n >> 6, dh = n & 63;
            *(ush8*)(outp + ((size_t)(b * NH + h) * NL + l) * NDH + dh) = v;
        }
    } else {
        // TS2[n][m]: stage transposed, write [dh][L] coalesced
#pragma unroll
        for (int mf = 0; mf < 4; ++mf)
#pragma unroll
            for (int nf = 0; nf < 4; ++nf) {
                int n = wn + nf * 16 + lr;
                int mc = (wm + mf * 16 + lg * 4) ^ ((n & 7) << 3);
                ush4 pk;
#pragma unroll
                for (int r = 0; r < 4; ++r) pk[r] = f2bf(acc[mf][nf][r] + bi[nf]);
                *(ush4*)&TS[n * 128 + mc] = pk;
            }
        __syncthreads();
#pragma unroll
        for (int p = 0; p < 8; ++p) {
            int u = t + p * 256;
            int r = u >> 4, sg = (u & 15) * 8;
            ush8 v = *(const ush8*)&TS[r * 128 + (sg ^ ((r & 7) << 3))];
            int n = nb + r;
            int h = n >> 6, dh = n & 63;
            int m0 = mt * 128 + sg;
            int b = m0 >> 11, l0 = m0 & (NL - 1);
            *(ush8*)(Vtb + ((size_t)(b * NH + h) * NDH + dh) * NL + l0) = v;
        }
    }
}

// ---------------------------------------------------------------------------
// Column stats + V prescale. Z[bh][j] = sum_i exp(SCALE*Q_i.K_j); then
// Vt[bh][dh][j] *= 1/Z_j in place. Block: (j-tile 128, bh).
// ---------------------------------------------------------------------------
__global__ __launch_bounds__(256, 3) void k_colsum_mfma(
    const unsigned short* __restrict__ Qb, const unsigned short* __restrict__ Kb,
    unsigned short* __restrict__ Vtb)
{
    __shared__ unsigned short Ks[128 * 64];   // [j][d], xor-swz
    __shared__ unsigned short Qs[64 * 64];    // [i][d], xor-swz
    __shared__ float rzbuf[128];

    const int jt = blockIdx.x;    // 0..15
    const int bh = blockIdx.y;    // 0..31
    const unsigned short* Qp = Qb + (size_t)bh * NL * NDH;
    const unsigned short* Kp = Kb + (size_t)bh * NL * NDH;
    const int t = threadIdx.x, w = t >> 6, lane = t & 63;
    const int lr = lane & 15, lg = lane >> 4;
    const int wj = w * 32;
    const int swz = (lr & 7) << 3;

#pragma unroll
    for (int p = 0; p < 4; ++p) {
        int u = t + p * 256;
        int r = u >> 3, sg = (u & 7) * 8;
        *(ush8*)&Ks[r * 64 + (sg ^ ((r & 7) << 3))] =
            *(const ush8*)(Kp + (size_t)(jt * 128 + r) * NDH + sg);
    }

    float zacc[2][4] = {};

    for (int it = 0; it < 32; ++it) {
        __syncthreads();
#pragma unroll
        for (int p = 0; p < 2; ++p) {
            int u = t + p * 256;
            int r = u >> 3, sg = (u & 7) * 8;
            *(ush8*)&Qs[r * 64 + (sg ^ ((r & 7) << 3))] =
                *(const ush8*)(Qp + (size_t)(it * 64 + r) * NDH + sg);
        }
        __syncthreads();

        bhalf8 ka[2][2], qv[4][2];
#pragma unroll
        for (int jf = 0; jf < 2; ++jf)
#pragma unroll
            for (int ks = 0; ks < 2; ++ks)
                ka[jf][ks] = *(const bhalf8*)&Ks[(wj + jf * 16 + lr) * 64 +
                                                ((ks * 32 + lg * 8) ^ swz)];
#pragma unroll
        for (int ii = 0; ii < 4; ++ii)
#pragma unroll
            for (int ks = 0; ks < 2; ++ks)
                qv[ii][ks] = *(const bhalf8*)&Qs[(ii * 16 + lr) * 64 +
                                                ((ks * 32 + lg * 8) ^ swz)];

#pragma unroll
        for (int jf = 0; jf < 2; ++jf)
#pragma unroll
            for (int ii = 0; ii < 4; ++ii) {
                f32x4 s = {};
                s = MFMA_BF16(ka[jf][0], qv[ii][0], s);
                s = MFMA_BF16(ka[jf][1], qv[ii][1], s);
#pragma unroll
                for (int r = 0; r < 4; ++r)
                    zacc[jf][r] += __expf(s[r] * SCALE);
            }
    }

    // reduce over 16 lanes holding different i
#pragma unroll
    for (int jf = 0; jf < 2; ++jf)
#pragma unroll
        for (int r = 0; r < 4; ++r) {
            float v = zacc[jf][r];
            v += __shfl_xor(v, 1);
            v += __shfl_xor(v, 2);
            v += __shfl_xor(v, 4);
            v += __shfl_xor(v, 8);
            zacc[jf][r] = v;
        }
    if (lr == 0) {
#pragma unroll
        for (int jf = 0; jf < 2; ++jf)
#pragma unroll
            for (int r = 0; r < 4; ++r)
                rzbuf[wj + jf * 16 + lg * 4 + r] = 1.0f / zacc[jf][r];
    }
    __syncthreads();

    // scale Vt[bh][0..63][jt*128 .. +128) in place
    unsigned short* Vp = Vtb + (size_t)bh * NDH * NL + jt * 128;
#pragma unroll
    for (int p = 0; p < 4; ++p) {
        int u = t + p * 256;
        int dh = u >> 4, jj = (u & 15) * 8;
        unsigned short* vp = Vp + (size_t)dh * NL + jj;
        ush8 v = *(const ush8*)vp;
        float4 z0 = *(const float4*)&rzbuf[jj];
        float4 z1 = *(const float4*)&rzbuf[jj + 4];
        uint4 o;
        o.x = pack_bf16(bf2f(v[0]) * z0.x, bf2f(v[1]) * z0.y);
        o.y = pack_bf16(bf2f(v[2]) * z0.z, bf2f(v[3]) * z0.w);
        o.z = pack_bf16(bf2f(v[4]) * z1.x, bf2f(v[5]) * z1.y);
        o.w = pack_bf16(bf2f(v[6]) * z1.z, bf2f(v[7]) * z1.w);
        *(uint4*)vp = o;
    }
}

// ---------------------------------------------------------------------------
// O[i][dh] = sum_j exp(SCALE*S_ij) * Vscaled[j][dh]. Block: (i-tile 128, bh).
// V already prescaled by 1/Z. P through xor-swizzled LDS. AO head-concat bf16.
// ---------------------------------------------------------------------------
__global__ __launch_bounds__(256, 3) void k_av_mfma(
    const unsigned short* __restrict__ Qb, const unsigned short* __restrict__ Kb,
    const unsigned short* __restrict__ Vtb, unsigned short* __restrict__ AOb)
{
    __shared__ unsigned short Qs[128 * 64];   // [i][d]  xor-swz
    __shared__ unsigned short Ks[64 * 64];    // [j][d]  xor-swz
    __shared__ unsigned short Vts[64 * 64];   // [dh][j] xor-swz (prescaled)
    __shared__ unsigned short Ps[128 * 64];   // [i][j]  xor-swz

    const int it = blockIdx.x;   // 0..15
    const int bh = blockIdx.y;   // 0..31
    const int b = bh >> 4, h = bh & 15;
    const unsigned short* Qp = Qb  + (size_t)bh * NL * NDH;
    const unsigned short* Kp = Kb  + (size_t)bh * NL * NDH;
    const unsigned short* Vp = Vtb + (size_t)bh * NDH * NL;

    const int t = threadIdx.x, w = t >> 6, lane = t & 63;
    const int lr = lane & 15, lg = lane >> 4;
    const int wi = w * 32;
    const int swz = (lr & 7) << 3;

#pragma unroll
    for (int p = 0; p < 4; ++p) {            // Q tile 128x64, once
        int u = t + p * 256;
        int r = u >> 3, sg = (u & 7) * 8;
        *(ush8*)&Qs[r * 64 + (sg ^ ((r & 7) << 3))] =
            *(const ush8*)(Qp + (size_t)(it * 128 + r) * NDH + sg);
    }

    f32x4 oacc[2][4] = {};

    for (int jt = 0; jt < 32; ++jt) {
        __syncthreads();
#pragma unroll
        for (int p = 0; p < 2; ++p) {        // K [64 j][64 d], Vt [64 dh][64 j]
            int u = t + p * 256;
            int r = u >> 3, sg = (u & 7) * 8;
            int sc = sg ^ ((r & 7) << 3);
            *(ush8*)&Ks[r * 64 + sc]  = *(const ush8*)(Kp + (size_t)(jt * 64 + r) * NDH + sg);
            *(ush8*)&Vts[r * 64 + sc] = *(const ush8*)(Vp + (size_t)r * NL + jt * 64 + sg);
        }
        __syncthreads();

        // S^T phase: A=K rows j, B=Q rows i
        bhalf8 ka[4][2], qv[2][2];
#pragma unroll
        for (int jf = 0; jf < 4; ++jf)
#pragma unroll
            for (int ks = 0; ks < 2; ++ks)
                ka[jf][ks] = *(const bhalf8*)&Ks[(jf * 16 + lr) * 64 +
                                                ((ks * 32 + lg * 8) ^ swz)];
#pragma unroll
        for (int ii = 0; ii < 2; ++ii)
#pragma unroll
            for (int ks = 0; ks < 2; ++ks)
                qv[ii][ks] = *(const bhalf8*)&Qs[(wi + ii * 16 + lr) * 64 +
                                                ((ks * 32 + lg * 8) ^ swz)];

#pragma unroll
        for (int ii = 0; ii < 2; ++ii)
#pragma unroll
            for (int jf = 0; jf < 4; ++jf) {
                f32x4 s = {};
                s = MFMA_BF16(ka[jf][0], qv[ii][0], s);
                s = MFMA_BF16(ka[jf][1], qv[ii][1], s);
                uint2 pk;
                pk.x = pack_bf16(__expf(s[0] * SCALE), __expf(s[1] * SCALE));
                pk.y = pack_bf16(__expf(s[2] * SCALE), __expf(s[3] * SCALE));
                // P[i = wi+ii*16+lr][j = jf*16+lg*4 .. +4]
                *(uint2*)&Ps[(wi + ii * 16 + lr) * 64 + ((jf * 16 + lg * 4) ^ swz)] = pk;
            }
        __syncthreads();

        // PV phase: A = P rows i, B = Vts rows dh
        bhalf8 pa[2][2], vb[4][2];
#pragma unroll
        for (int ii = 0; ii < 2; ++ii)
#pragma unroll
            for (int ks = 0; ks < 2; ++ks)
                pa[ii][ks] = *(const bhalf8*)&Ps[(wi + ii * 16 + lr) * 64 +
                                                ((ks * 32 + lg * 8) ^ swz)];
#pragma unroll
        for (int nf = 0; nf < 4; ++nf)
#pragma unroll
            for (int ks = 0; ks < 2; ++ks)
                vb[nf][ks] = *(const bhalf8*)&Vts[(nf * 16 + lr) * 64 +
                                                 ((ks * 32 + lg * 8) ^ swz)];
#pragma unroll
        for (int ii = 0; ii < 2; ++ii)
#pragma unroll
            for (int nf = 0; nf < 4; ++nf) {
                oacc[ii][nf] = MFMA_BF16(pa[ii][0], vb[nf][0], oacc[ii][nf]);
                oacc[ii][nf] = MFMA_BF16(pa[ii][1], vb[nf][1], oacc[ii][nf]);
            }
    }

    // epilogue: transpose-stage via Ps, write AO coalesced
    __syncthreads();
#pragma unroll
    for (int ii = 0; ii < 2; ++ii)
#pragma unroll
        for (int nf = 0; nf < 4; ++nf)
#pragma unroll
            for (int r = 0; r < 4; ++r) {
                int l  = wi + ii * 16 + lg * 4 + r;
                int dh = (nf * 16 + lr) ^ ((l & 7) << 3);
                Ps[l * 64 + dh] = f2bf(oacc[ii][nf][r]);
            }
    __syncthreads();
#pragma unroll
    for (int p = 0; p < 4; ++p) {
        int u = t + p * 256;
        int r = u >> 3, sg = (u & 7) * 8;
        ush8 v = *(const ush8*)&Ps[r * 64 + (sg ^ ((r & 7) << 3))];
        *(ush8*)(AOb + ((size_t)(b * NL + it * 128 + r)) * ND + h * NDH + sg) = v;
    }
}

// ---------------------------------------------------------------------------
// Output projection: y[m][e] = sum_d AO[m][d]*WO[e][d] + bO[e]. 128x128, BK=64.
// ---------------------------------------------------------------------------
__global__ __launch_bounds__(256, 2) void k_oproj_mfma(
    const unsigned short* __restrict__ AOb, const unsigned short* __restrict__ WOb,
    const float* __restrict__ bO, float* __restrict__ y)
{
    __shared__ unsigned short As[128 * 64];
    __shared__ unsigned short Bs[128 * 64];

    const int mt = blockIdx.x;   // 0..31
    const int nt = blockIdx.y;   // 0..7
    const int t = threadIdx.x, w = t >> 6, lane = t & 63;
    const int lr = lane & 15, lg = lane >> 4;
    const int wm = (w >> 1) * 64, wn = (w & 1) * 64;
    const int swz = (lr & 7) << 3;

    f32x4 acc[4][4] = {};

    for (int k0 = 0; k0 < ND; k0 += 64) {
        __syncthreads();
#pragma unroll
        for (int p = 0; p < 4; ++p) {
            int u = t + p * 256;
            int r = u >> 3, sg = (u & 7) * 8;
            int sc = sg ^ ((r & 7) << 3);
            *(ush8*)&As[r * 64 + sc] = *(const ush8*)(AOb + (size_t)(mt * 128 + r) * ND + k0 + sg);
            *(ush8*)&Bs[r * 64 + sc] = *(const ush8*)(WOb + (size_t)(nt * 128 + r) * ND + k0 + sg);
        }
        __syncthreads();

        bhalf8 av[4][2], bw[4][2];
#pragma unroll
        for (int f = 0; f < 4; ++f)
#pragma unroll
            for (int ks = 0; ks < 2; ++ks) {
                int c = (ks * 32 + lg * 8) ^ swz;
                av[f][ks] = *(const bhalf8*)&As[(wm + f * 16 + lr) * 64 + c];
                bw[f][ks] = *(const bhalf8*)&Bs[(wn + f * 16 + lr) * 64 + c];
            }
#pragma unroll
        for (int mf = 0; mf < 4; ++mf)
#pragma unroll
            for (int nf = 0; nf < 4; ++nf) {
                acc[mf][nf] = MFMA_BF16(av[mf][0], bw[nf][0], acc[mf][nf]);
                acc[mf][nf] = MFMA_BF16(av[mf][1], bw[nf][1], acc[mf][nf]);
            }
    }

#pragma unroll
    for (int mf = 0; mf < 4; ++mf)
#pragma unroll
        for (int nf = 0; nf < 4; ++nf) {
            int e = nt * 128 + wn + nf * 16 + lr;
            float bo = bO[e];
#pragma unroll
            for (int r = 0; r < 4; ++r) {
                int m = mt * 128 + wm + mf * 16 + lg * 4 + r;
                y[(size_t)m * ND + e] = acc[mf][nf][r] + bo;
            }
        }
}

// ---------------------------------------------------------------------------
extern "C" void kernel_launch(void* const* d_in, const int* in_sizes, int n_in,
                              void* d_out, int out_size, void* d_ws, size_t ws_size,
                              hipStream_t stream)
{
    const float* x  = (const float*)d_in[0];
    const float* Wq = (const float*)d_in[1];
    const float* bq = (const float*)d_in[2];
    const float* Wk = (const float*)d_in[3];
    const float* bk = (const float*)d_in[4];
    const float* Wv = (const float*)d_in[5];
    const float* bv = (const float*)d_in[6];
    const float* WO = (const float*)d_in[7];
    const float* bO = (const float*)d_in[8];
    float* y = (float*)d_out;

    unsigned short* xb  = (unsigned short*)d_ws;     // 4,194,304 (8 MB)
    unsigned short* Wtb = xb  + 4194304;             // 3,145,728 (6 MB)
    unsigned short* WOb = Wtb + 3145728;             // 1,048,576 (2 MB)
    unsigned short* Qb  = WOb + 1048576;             // 4,194,304 (8 MB)
    unsigned short* Kb  = Qb  + 4194304;             // 4,194,304 (8 MB)
    unsigned short* Vtb = Kb  + 4194304;             // 4,194,304 (8 MB)
    unsigned short* AOb = Vtb + 4194304;             // 4,194,304 (8 MB)

    hipLaunchKernelGGL(k_cvt,         dim3(2560),   dim3(256), 0, stream, x, WO, xb, WOb);
    hipLaunchKernelGGL(k_cvt_wt,      dim3(16, 48), dim3(256), 0, stream, Wq, Wk, Wv, Wtb);
    hipLaunchKernelGGL(k_qkv_mfma,    dim3(32, 24), dim3(256), 0, stream,
                       xb, Wtb, bq, bk, bv, Qb, Kb, Vtb);
    hipLaunchKernelGGL(k_colsum_mfma, dim3(16, 32), dim3(256), 0, stream, Qb, Kb, Vtb);
    hipLaunchKernelGGL(k_av_mfma,     dim3(16, 32), dim3(256), 0, stream, Qb, Kb, Vtb, AOb);
    hipLaunchKernelGGL(k_oproj_mfma,  dim3(32, 8),  dim3(256), 0, stream, AOb, WOb, bO, y);
}

// Round 5
// 215.699 us; speedup vs baseline: 6.1261x; 1.0748x over previous
//
#include <hip/hip_runtime.h>
#include <math.h>

#define NB 2
#define NL 2048
#define ND 1024
#define NH 16
#define NDH 64
static constexpr float SCALE = 0.125f;   // 1/sqrt(64)

typedef short          bhalf8 __attribute__((ext_vector_type(8)));   // 8 bf16 (4 VGPR)
typedef unsigned short ush8   __attribute__((ext_vector_type(8)));
typedef unsigned short ush4   __attribute__((ext_vector_type(4)));
typedef float          f32x4  __attribute__((ext_vector_type(4)));

#define MFMA_BF16(a, b, c) __builtin_amdgcn_mfma_f32_16x16x32_bf16(a, b, c, 0, 0, 0)

__device__ __forceinline__ unsigned short f2bf(float f) {
    unsigned u = __float_as_uint(f);
    u += 0x7FFF + ((u >> 16) & 1);           // RNE
    return (unsigned short)(u >> 16);
}
__device__ __forceinline__ float bf2f(unsigned short s) {
    return __uint_as_float((unsigned)s << 16);
}
// pack two floats to two bf16 in ONE dword: [15:0]=lo, [31:16]=hi
__device__ __forceinline__ unsigned pack_bf16(float lo, float hi) {
    unsigned a = __float_as_uint(lo) + 0x8000u;
    unsigned b = __float_as_uint(hi) + 0x8000u;
    return __builtin_amdgcn_perm(b, a, 0x07060302u);
}
// async global->LDS, 16B per lane. lds dest must be wave-uniform base (+lane*16).
__device__ __forceinline__ void gload16(const unsigned short* g, unsigned short* l) {
    __builtin_amdgcn_global_load_lds(
        (const __attribute__((address_space(1))) unsigned int*)(const void*)g,
        (__attribute__((address_space(3))) unsigned int*)(void*)l,
        16, 0, 0);
}

// ---------------------------------------------------------------------------
// Convert 1: fp32->bf16 for x (4M elems) then WO (1M elems).
// ---------------------------------------------------------------------------
__global__ __launch_bounds__(256) void k_cvt(
    const float* __restrict__ x, const float* __restrict__ WO,
    unsigned short* __restrict__ xb, unsigned short* __restrict__ wob)
{
    size_t u = (size_t)blockIdx.x * 256 + threadIdx.x;
    const float* src; unsigned short* dst; size_t off;
    if (u < 524288) { src = x;  dst = xb;  off = u * 8; }
    else            { src = WO; dst = wob; off = (u - 524288) * 8; }
    float4 a = *(const float4*)(src + off);
    float4 b = *(const float4*)(src + off + 4);
    uint4 o;
    o.x = pack_bf16(a.x, a.y); o.y = pack_bf16(a.z, a.w);
    o.z = pack_bf16(b.x, b.y); o.w = pack_bf16(b.z, b.w);
    *(uint4*)(dst + off) = o;
}

// ---------------------------------------------------------------------------
// Convert 2: Wq/Wk/Wv [h][1024 d][64 dh] fp32 -> Wtb [qkv][h][64 dh][1024 d] bf16
// ---------------------------------------------------------------------------
__global__ __launch_bounds__(256) void k_cvt_wt(
    const float* __restrict__ Wq, const float* __restrict__ Wk,
    const float* __restrict__ Wv, unsigned short* __restrict__ Wtb)
{
    __shared__ unsigned short T[64][72];
    const int d0  = blockIdx.x * 64;
    const int qkv = blockIdx.y >> 4;
    const int h   = blockIdx.y & 15;
    const float* W = (qkv == 0 ? Wq : (qkv == 1 ? Wk : Wv)) + (size_t)h * (ND * NDH);
    const int t = threadIdx.x;
#pragma unroll
    for (int p = 0; p < 4; ++p) {
        int u  = t + p * 256;
        int dr = u >> 4;
        int c4 = (u & 15) * 4;
        float4 v = *(const float4*)(W + (size_t)(d0 + dr) * NDH + c4);
        T[c4 + 0][dr] = f2bf(v.x);
        T[c4 + 1][dr] = f2bf(v.y);
        T[c4 + 2][dr] = f2bf(v.z);
        T[c4 + 3][dr] = f2bf(v.w);
    }
    __syncthreads();
    unsigned short* outp = Wtb + (size_t)(qkv * NH + h) * NDH * ND;
#pragma unroll
    for (int p = 0; p < 2; ++p) {
        int u  = t + p * 256;
        int dh = u >> 3;
        int sg = (u & 7) * 8;
        *(ush8*)(outp + (size_t)dh * ND + d0 + sg) = *(ush8*)&T[dh][sg];
    }
}

// ---------------------------------------------------------------------------
// QKV projection as ONE GEMM: out[m][n] = sum_d xb[m][d]*Wtb[n][d],
// m=4096, n=3072, 128x128 tile, BK=64, 4 waves (2x2 of 64x64).
// Staging via global_load_lds with pre-swizzled source.
// ---------------------------------------------------------------------------
__global__ __launch_bounds__(256, 2) void k_qkv_mfma(
    const unsigned short* __restrict__ xb, const unsigned short* __restrict__ Wtb,
    const float* __restrict__ bq, const float* __restrict__ bk,
    const float* __restrict__ bv,
    unsigned short* __restrict__ Qb, unsigned short* __restrict__ Kb,
    unsigned short* __restrict__ Vtb)
{
    __shared__ unsigned short LB[2 * 128 * 64];   // As|Bs, reused as TS[128][128]
    unsigned short* As = LB;
    unsigned short* Bs = LB + 128 * 64;

    const int mt = blockIdx.x;   // 0..31
    const int nt = blockIdx.y;   // 0..23
    const int qkv = nt >> 3;
    const int t = threadIdx.x, w = t >> 6, lane = t & 63;
    const int lr = lane & 15, lg = lane >> 4;
    const int wm = (w >> 1) * 64, wn = (w & 1) * 64;
    const int swz = (lr & 7) << 3;
    const int rA = lane >> 3, cg = (lane & 7) * 8;

    f32x4 acc[4][4] = {};

    for (int k0 = 0; k0 < ND; k0 += 64) {
        __syncthreads();
#pragma unroll
        for (int i = 0; i < 4; ++i) {            // 16 chunks each, 4/wave
            int c  = w * 4 + i;
            int r  = c * 8 + rA;
            int gc = cg ^ ((r & 7) << 3);
            gload16(xb  + (size_t)(mt * 128 + r) * ND + k0 + gc, &As[c * 512]);
            gload16(Wtb + (size_t)(nt * 128 + r) * ND + k0 + gc, &Bs[c * 512]);
        }
        __syncthreads();

        bhalf8 av[4][2], bw[4][2];
#pragma unroll
        for (int f = 0; f < 4; ++f)
#pragma unroll
            for (int ks = 0; ks < 2; ++ks) {
                int c = (ks * 32 + lg * 8) ^ swz;
                av[f][ks] = *(const bhalf8*)&As[(wm + f * 16 + lr) * 64 + c];
                bw[f][ks] = *(const bhalf8*)&Bs[(wn + f * 16 + lr) * 64 + c];
            }
#pragma unroll
        for (int mf = 0; mf < 4; ++mf)
#pragma unroll
            for (int nf = 0; nf < 4; ++nf) {
                acc[mf][nf] = MFMA_BF16(av[mf][0], bw[nf][0], acc[mf][nf]);
                acc[mf][nf] = MFMA_BF16(av[mf][1], bw[nf][1], acc[mf][nf]);
            }
    }

    const float* bias = (qkv == 0 ? bq : (qkv == 1 ? bk : bv));
    const int nb = (nt & 7) * 128;
    float bi[4];
#pragma unroll
    for (int nf = 0; nf < 4; ++nf) bi[nf] = bias[nb + wn + nf * 16 + lr];

    __syncthreads();                    // done with As/Bs
    unsigned short* TS = LB;            // [128][128], xor-swizzled

    if (qkv < 2) {
#pragma unroll
        for (int mf = 0; mf < 4; ++mf)
#pragma unroll
            for (int nf = 0; nf < 4; ++nf)
#pragma unroll
                for (int r = 0; r < 4; ++r) {
                    int m = wm + mf * 16 + lg * 4 + r;
                    int n = (wn + nf * 16 + lr) ^ ((m & 7) << 3);
                    TS[m * 128 + n] = f2bf(acc[mf][nf][r] + bi[nf]);
                }
        __syncthreads();
        unsigned short* outp = (qkv == 0 ? Qb : Kb);
#pragma unroll
        for (int p = 0; p < 8; ++p) {
            int u = t + p * 256;
            int r = u >> 4, sg = (u & 15) * 8;
            ush8 v = *(const ush8*)&TS[r * 128 + (sg ^ ((r & 7) << 3))];
            int m = mt * 128 + r;
            int b = m >> 11, l = m & (NL - 1);
            int n = nb + sg;
            int h = n >> 6, dh = n & 63;
            *(ush8*)(outp + ((size_t)(b * NH + h) * NL + l) * NDH + dh) = v;
        }
    } else {
#pragma unroll
        for (int mf = 0; mf < 4; ++mf)
#pragma unroll
            for (int nf = 0; nf < 4; ++nf) {
                int n = wn + nf * 16 + lr;
                int mc = (wm + mf * 16 + lg * 4) ^ ((n & 7) << 3);
                ush4 pk;
#pragma unroll
                for (int r = 0; r < 4; ++r) pk[r] = f2bf(acc[mf][nf][r] + bi[nf]);
                *(ush4*)&TS[n * 128 + mc] = pk;
            }
        __syncthreads();
#pragma unroll
        for (int p = 0; p < 8; ++p) {
            int u = t + p * 256;
            int r = u >> 4, sg = (u & 15) * 8;
            ush8 v = *(const ush8*)&TS[r * 128 + (sg ^ ((r & 7) << 3))];
            int n = nb + r;
            int h = n >> 6, dh = n & 63;
            int m0 = mt * 128 + sg;
            int b = m0 >> 11, l0 = m0 & (NL - 1);
            *(ush8*)(Vtb + ((size_t)(b * NH + h) * NDH + dh) * NL + l0) = v;
        }
    }
}

// ---------------------------------------------------------------------------
// Column stats + V prescale. 512 threads, 8 waves; wave owns 16 j rows.
// Z[bh][j] = sum_i exp(SCALE*Q_i.K_j); then Vt[bh][dh][j] *= 1/Z_j in place.
// ---------------------------------------------------------------------------
__global__ __launch_bounds__(512, 4) void k_colsum_mfma(
    const unsigned short* __restrict__ Qb, const unsigned short* __restrict__ Kb,
    unsigned short* __restrict__ Vtb)
{
    __shared__ unsigned short Ks[128 * 64];   // [j][d], xor-swz
    __shared__ unsigned short Qs[64 * 64];    // [i][d], xor-swz
    __shared__ float rzbuf[128];

    const int jt = blockIdx.x;    // 0..15
    const int bh = blockIdx.y;    // 0..31
    const unsigned short* Qp = Qb + (size_t)bh * NL * NDH;
    const unsigned short* Kp = Kb + (size_t)bh * NL * NDH;
    const int t = threadIdx.x, w = t >> 6, lane = t & 63;
    const int lr = lane & 15, lg = lane >> 4;
    const int wj = w * 16;
    const int swz = (lr & 7) << 3;
    const int rA = lane >> 3, cg = (lane & 7) * 8;

    // K tile 128x64 staged once: 16 chunks, 2/wave
#pragma unroll
    for (int i = 0; i < 2; ++i) {
        int c  = w * 2 + i;
        int r  = c * 8 + rA;
        int gc = cg ^ ((r & 7) << 3);
        gload16(Kp + (size_t)(jt * 128 + r) * NDH + gc, &Ks[c * 512]);
    }

    float zacc[4] = {};

    for (int it = 0; it < 32; ++it) {
        __syncthreads();                 // prev Qs reads done
        {                                // Q tile 64x64: 8 chunks, 1/wave
            int r  = w * 8 + rA;
            int gc = cg ^ ((r & 7) << 3);
            gload16(Qp + (size_t)(it * 64 + r) * NDH + gc, &Qs[w * 512]);
        }
        __syncthreads();                 // Q (and K, iter0) staged

        bhalf8 ka[2];
#pragma unroll
        for (int ks = 0; ks < 2; ++ks)
            ka[ks] = *(const bhalf8*)&Ks[(wj + lr) * 64 + ((ks * 32 + lg * 8) ^ swz)];
#pragma unroll
        for (int ii = 0; ii < 4; ++ii) {
            bhalf8 q0 = *(const bhalf8*)&Qs[(ii * 16 + lr) * 64 + ((lg * 8) ^ swz)];
            bhalf8 q1 = *(const bhalf8*)&Qs[(ii * 16 + lr) * 64 + ((32 + lg * 8) ^ swz)];
            f32x4 s = {};
            s = MFMA_BF16(ka[0], q0, s);
            s = MFMA_BF16(ka[1], q1, s);
#pragma unroll
            for (int r = 0; r < 4; ++r) zacc[r] += __expf(s[r] * SCALE);
        }
    }

    // reduce over the 16 lanes holding different i
#pragma unroll
    for (int r = 0; r < 4; ++r) {
        float v = zacc[r];
        v += __shfl_xor(v, 1);
        v += __shfl_xor(v, 2);
        v += __shfl_xor(v, 4);
        v += __shfl_xor(v, 8);
        if (lr == 0) rzbuf[wj + lg * 4 + r] = 1.0f / v;
    }
    __syncthreads();

    // scale Vt[bh][0..63][jt*128 .. +128) in place: 512 thr x 16 elems
    unsigned short* Vp = Vtb + (size_t)bh * NDH * NL + jt * 128;
    {
        int dh = t >> 3, jj = (t & 7) * 16;
        unsigned short* vp = Vp + (size_t)dh * NL + jj;
        ush8 v0 = *(const ush8*)vp;
        ush8 v1 = *(const ush8*)(vp + 8);
        float4 z0 = *(const float4*)&rzbuf[jj];
        float4 z1 = *(const float4*)&rzbuf[jj + 4];
        float4 z2 = *(const float4*)&rzbuf[jj + 8];
        float4 z3 = *(const float4*)&rzbuf[jj + 12];
        uint4 o0, o1;
        o0.x = pack_bf16(bf2f(v0[0]) * z0.x, bf2f(v0[1]) * z0.y);
        o0.y = pack_bf16(bf2f(v0[2]) * z0.z, bf2f(v0[3]) * z0.w);
        o0.z = pack_bf16(bf2f(v0[4]) * z1.x, bf2f(v0[5]) * z1.y);
        o0.w = pack_bf16(bf2f(v0[6]) * z1.z, bf2f(v0[7]) * z1.w);
        o1.x = pack_bf16(bf2f(v1[0]) * z2.x, bf2f(v1[1]) * z2.y);
        o1.y = pack_bf16(bf2f(v1[2]) * z2.z, bf2f(v1[3]) * z2.w);
        o1.z = pack_bf16(bf2f(v1[4]) * z3.x, bf2f(v1[5]) * z3.y);
        o1.w = pack_bf16(bf2f(v1[6]) * z3.z, bf2f(v1[7]) * z3.w);
        *(uint4*)vp = o0;
        *(uint4*)(vp + 8) = o1;
    }
}

// ---------------------------------------------------------------------------
// O[i][dh] = sum_j exp(SCALE*S_ij) * Vscaled[j][dh]. 512 threads, 8 waves;
// wave owns 16 i rows. P tile is wave-private (no barrier between S and PV).
// ---------------------------------------------------------------------------
__global__ __launch_bounds__(512, 4) void k_av_mfma(
    const unsigned short* __restrict__ Qb, const unsigned short* __restrict__ Kb,
    const unsigned short* __restrict__ Vtb, unsigned short* __restrict__ AOb)
{
    __shared__ unsigned short Qs[128 * 64];   // [i][d]  xor-swz
    __shared__ unsigned short Ks[64 * 64];    // [j][d]  xor-swz
    __shared__ unsigned short Vts[64 * 64];   // [dh][j] xor-swz (prescaled)
    __shared__ unsigned short Ps[128 * 64];   // [i][j]  xor-swz, wave-private rows

    const int it = blockIdx.x;   // 0..15
    const int bh = blockIdx.y;   // 0..31
    const int b = bh >> 4, h = bh & 15;
    const unsigned short* Qp = Qb  + (size_t)bh * NL * NDH;
    const unsigned short* Kp = Kb  + (size_t)bh * NL * NDH;
    const unsigned short* Vp = Vtb + (size_t)bh * NDH * NL;

    const int t = threadIdx.x, w = t >> 6, lane = t & 63;
    const int lr = lane & 15, lg = lane >> 4;
    const int wi = w * 16;
    const int swz = (lr & 7) << 3;
    const int rA = lane >> 3, cg = (lane & 7) * 8;

    // Q tile 128x64 staged once: 16 chunks, 2/wave
#pragma unroll
    for (int i = 0; i < 2; ++i) {
        int c  = w * 2 + i;
        int r  = c * 8 + rA;
        int gc = cg ^ ((r & 7) << 3);
        gload16(Qp + (size_t)(it * 128 + r) * NDH + gc, &Qs[c * 512]);
    }

    f32x4 oacc[4] = {};

    for (int jt = 0; jt < 32; ++jt) {
        __syncthreads();                 // prev-iter Ks/Vts reads done
        {                                // K and Vt: 8 chunks each, 1/wave
            int r  = w * 8 + rA;
            int gc = cg ^ ((r & 7) << 3);
            gload16(Kp + (size_t)(jt * 64 + r) * NDH + gc, &Ks[w * 512]);
            gload16(Vp + (size_t)r * NL + jt * 64 + gc,    &Vts[w * 512]);
        }
        __syncthreads();                 // staged (and Qs on jt=0)

        // S^T phase: A=K rows j, B=Q rows i -> P[i][j] (own 16 i rows)
        bhalf8 qa[2];
#pragma unroll
        for (int ks = 0; ks < 2; ++ks)
            qa[ks] = *(const bhalf8*)&Qs[(wi + lr) * 64 + ((ks * 32 + lg * 8) ^ swz)];
#pragma unroll
        for (int jf = 0; jf < 4; ++jf) {
            bhalf8 k0v = *(const bhalf8*)&Ks[(jf * 16 + lr) * 64 + ((lg * 8) ^ swz)];
            bhalf8 k1v = *(const bhalf8*)&Ks[(jf * 16 + lr) * 64 + ((32 + lg * 8) ^ swz)];
            f32x4 s = {};
            s = MFMA_BF16(k0v, qa[0], s);
            s = MFMA_BF16(k1v, qa[1], s);
            uint2 pk;
            pk.x = pack_bf16(__expf(s[0] * SCALE), __expf(s[1] * SCALE));
            pk.y = pack_bf16(__expf(s[2] * SCALE), __expf(s[3] * SCALE));
            *(uint2*)&Ps[(wi + lr) * 64 + ((jf * 16 + lg * 4) ^ swz)] = pk;
        }
        // no barrier: Ps rows [wi, wi+16) are written and read by this wave only

        // PV phase: A = P rows i, B = Vts rows dh
        bhalf8 pa[2];
#pragma unroll
        for (int ks = 0; ks < 2; ++ks)
            pa[ks] = *(const bhalf8*)&Ps[(wi + lr) * 64 + ((ks * 32 + lg * 8) ^ swz)];
#pragma unroll
        for (int nf = 0; nf < 4; ++nf) {
            bhalf8 v0 = *(const bhalf8*)&Vts[(nf * 16 + lr) * 64 + ((lg * 8) ^ swz)];
            bhalf8 v1 = *(const bhalf8*)&Vts[(nf * 16 + lr) * 64 + ((32 + lg * 8) ^ swz)];
            oacc[nf] = MFMA_BF16(pa[0], v0, oacc[nf]);
            oacc[nf] = MFMA_BF16(pa[1], v1, oacc[nf]);
        }
    }

    // epilogue: transpose-stage own rows into Ps, then coalesced AO write
    __syncthreads();
#pragma unroll
    for (int nf = 0; nf < 4; ++nf)
#pragma unroll
        for (int r = 0; r < 4; ++r) {
            int li  = wi + lg * 4 + r;
            int dhc = (nf * 16 + lr) ^ ((li & 7) << 3);
            Ps[li * 64 + dhc] = f2bf(oacc[nf][r]);
        }
    __syncthreads();
    {
        int r = t >> 2, sgq = (t & 3) * 16;
        int sz2 = (r & 7) << 3;
        ush8 v0 = *(const ush8*)&Ps[r * 64 + (sgq ^ sz2)];
        ush8 v1 = *(const ush8*)&Ps[r * 64 + ((sgq + 8) ^ sz2)];
        unsigned short* op = AOb + ((size_t)(b * NL + it * 128 + r)) * ND + h * NDH + sgq;
        *(ush8*)op = v0;
        *(ush8*)(op + 8) = v1;
    }
}

// ---------------------------------------------------------------------------
// Output projection: y[m][e] = sum_d AO[m][d]*WO[e][d] + bO[e].
// 64(m) x 128(e) tile, BK=64, 4 waves each own 64m x 32e. Grid 512.
// ---------------------------------------------------------------------------
__global__ __launch_bounds__(256, 2) void k_oproj_mfma(
    const unsigned short* __restrict__ AOb, const unsigned short* __restrict__ WOb,
    const float* __restrict__ bO, float* __restrict__ y)
{
    __shared__ unsigned short As[64 * 64];    // AO rows m
    __shared__ unsigned short Bs[128 * 64];   // WO rows e

    const int mt = blockIdx.x;   // 0..63
    const int nt = blockIdx.y;   // 0..7
    const int t = threadIdx.x, w = t >> 6, lane = t & 63;
    const int lr = lane & 15, lg = lane >> 4;
    const int wn = w * 32;
    const int swz = (lr & 7) << 3;
    const int rA = lane >> 3, cg = (lane & 7) * 8;

    f32x4 acc[4][2] = {};

    for (int k0 = 0; k0 < ND; k0 += 64) {
        __syncthreads();
#pragma unroll
        for (int i = 0; i < 2; ++i) {            // A: 8 chunks, 2/wave
            int c  = w * 2 + i;
            int r  = c * 8 + rA;
            int gc = cg ^ ((r & 7) << 3);
            gload16(AOb + (size_t)(mt * 64 + r) * ND + k0 + gc, &As[c * 512]);
        }
#pragma unroll
        for (int i = 0; i < 4; ++i) {            // B: 16 chunks, 4/wave
            int c  = w * 4 + i;
            int r  = c * 8 + rA;
            int gc = cg ^ ((r & 7) << 3);
            gload16(WOb + (size_t)(nt * 128 + r) * ND + k0 + gc, &Bs[c * 512]);
        }
        __syncthreads();

        bhalf8 bw[2][2];
#pragma unroll
        for (int nf = 0; nf < 2; ++nf)
#pragma unroll
            for (int ks = 0; ks < 2; ++ks)
                bw[nf][ks] = *(const bhalf8*)&Bs[(wn + nf * 16 + lr) * 64 +
                                                ((ks * 32 + lg * 8) ^ swz)];
#pragma unroll
        for (int mf = 0; mf < 4; ++mf) {
            bhalf8 a0 = *(const bhalf8*)&As[(mf * 16 + lr) * 64 + ((lg * 8) ^ swz)];
            bhalf8 a1 = *(const bhalf8*)&As[(mf * 16 + lr) * 64 + ((32 + lg * 8) ^ swz)];
#pragma unroll
            for (int nf = 0; nf < 2; ++nf) {
                acc[mf][nf] = MFMA_BF16(a0, bw[nf][0], acc[mf][nf]);
                acc[mf][nf] = MFMA_BF16(a1, bw[nf][1], acc[mf][nf]);
            }
        }
    }

#pragma unroll
    for (int mf = 0; mf < 4; ++mf)
#pragma unroll
        for (int nf = 0; nf < 2; ++nf) {
            int e = nt * 128 + wn + nf * 16 + lr;
            float bo = bO[e];
#pragma unroll
            for (int r = 0; r < 4; ++r) {
                int m = mt * 64 + mf * 16 + lg * 4 + r;
                y[(size_t)m * ND + e] = acc[mf][nf][r] + bo;
            }
        }
}

// ---------------------------------------------------------------------------
extern "C" void kernel_launch(void* const* d_in, const int* in_sizes, int n_in,
                              void* d_out, int out_size, void* d_ws, size_t ws_size,
                              hipStream_t stream)
{
    const float* x  = (const float*)d_in[0];
    const float* Wq = (const float*)d_in[1];
    const float* bq = (const float*)d_in[2];
    const float* Wk = (const float*)d_in[3];
    const float* bk = (const float*)d_in[4];
    const float* Wv = (const float*)d_in[5];
    const float* bv = (const float*)d_in[6];
    const float* WO = (const float*)d_in[7];
    const float* bO = (const float*)d_in[8];
    float* y = (float*)d_out;

    unsigned short* xb  = (unsigned short*)d_ws;     // 4,194,304 (8 MB)
    unsigned short* Wtb = xb  + 4194304;             // 3,145,728 (6 MB)
    unsigned short* WOb = Wtb + 3145728;             // 1,048,576 (2 MB)
    unsigned short* Qb  = WOb + 1048576;             // 4,194,304 (8 MB)
    unsigned short* Kb  = Qb  + 4194304;             // 4,194,304 (8 MB)
    unsigned short* Vtb = Kb  + 4194304;             // 4,194,304 (8 MB)
    unsigned short* AOb = Vtb + 4194304;             // 4,194,304 (8 MB)

    hipLaunchKernelGGL(k_cvt,         dim3(2560),   dim3(256), 0, stream, x, WO, xb, WOb);
    hipLaunchKernelGGL(k_cvt_wt,      dim3(16, 48), dim3(256), 0, stream, Wq, Wk, Wv, Wtb);
    hipLaunchKernelGGL(k_qkv_mfma,    dim3(32, 24), dim3(256), 0, stream,
                       xb, Wtb, bq, bk, bv, Qb, Kb, Vtb);
    hipLaunchKernelGGL(k_colsum_mfma, dim3(16, 32), dim3(512), 0, stream, Qb, Kb, Vtb);
    hipLaunchKernelGGL(k_av_mfma,     dim3(16, 32), dim3(512), 0, stream, Qb, Kb, Vtb, AOb);
    hipLaunchKernelGGL(k_oproj_mfma,  dim3(64, 8),  dim3(256), 0, stream, AOb, WOb, bO, y);
}

// Round 6
// 215.077 us; speedup vs baseline: 6.1438x; 1.0029x over previous
//
#include <hip/hip_runtime.h>
#include <math.h>

#define NB 2
#define NL 2048
#define ND 1024
#define NH 16
#define NDH 64
static constexpr float SCALE = 0.125f;   // 1/sqrt(64)

typedef short          bhalf8 __attribute__((ext_vector_type(8)));   // 8 bf16 (4 VGPR)
typedef unsigned short ush8   __attribute__((ext_vector_type(8)));
typedef unsigned short ush4   __attribute__((ext_vector_type(4)));
typedef float          f32x4  __attribute__((ext_vector_type(4)));

#define MFMA_BF16(a, b, c) __builtin_amdgcn_mfma_f32_16x16x32_bf16(a, b, c, 0, 0, 0)

__device__ __forceinline__ unsigned short f2bf(float f) {
    unsigned u = __float_as_uint(f);
    u += 0x7FFF + ((u >> 16) & 1);           // RNE
    return (unsigned short)(u >> 16);
}
__device__ __forceinline__ float bf2f(unsigned short s) {
    return __uint_as_float((unsigned)s << 16);
}
// pack two floats to two bf16 in ONE dword: [15:0]=lo, [31:16]=hi
__device__ __forceinline__ unsigned pack_bf16(float lo, float hi) {
    unsigned a = __float_as_uint(lo) + 0x8000u;
    unsigned b = __float_as_uint(hi) + 0x8000u;
    return __builtin_amdgcn_perm(b, a, 0x07060302u);
}
// async global->LDS, 16B per lane. lds dest must be wave-uniform base (+lane*16).
__device__ __forceinline__ void gload16(const unsigned short* g, unsigned short* l) {
    __builtin_amdgcn_global_load_lds(
        (const __attribute__((address_space(1))) unsigned int*)(const void*)g,
        (__attribute__((address_space(3))) unsigned int*)(void*)l,
        16, 0, 0);
}

// ---------------------------------------------------------------------------
// Convert 1: fp32->bf16 for x (4M elems) then WO (1M elems).
// ---------------------------------------------------------------------------
__global__ __launch_bounds__(256) void k_cvt(
    const float* __restrict__ x, const float* __restrict__ WO,
    unsigned short* __restrict__ xb, unsigned short* __restrict__ wob)
{
    size_t u = (size_t)blockIdx.x * 256 + threadIdx.x;
    const float* src; unsigned short* dst; size_t off;
    if (u < 524288) { src = x;  dst = xb;  off = u * 8; }
    else            { src = WO; dst = wob; off = (u - 524288) * 8; }
    float4 a = *(const float4*)(src + off);
    float4 b = *(const float4*)(src + off + 4);
    uint4 o;
    o.x = pack_bf16(a.x, a.y); o.y = pack_bf16(a.z, a.w);
    o.z = pack_bf16(b.x, b.y); o.w = pack_bf16(b.z, b.w);
    *(uint4*)(dst + off) = o;
}

// ---------------------------------------------------------------------------
// Convert 2: Wq/Wk/Wv [h][1024 d][64 dh] fp32 -> Wtb [qkv][h][64 dh][1024 d] bf16
// ---------------------------------------------------------------------------
__global__ __launch_bounds__(256) void k_cvt_wt(
    const float* __restrict__ Wq, const float* __restrict__ Wk,
    const float* __restrict__ Wv, unsigned short* __restrict__ Wtb)
{
    __shared__ unsigned short T[64][72];
    const int d0  = blockIdx.x * 64;
    const int qkv = blockIdx.y >> 4;
    const int h   = blockIdx.y & 15;
    const float* W = (qkv == 0 ? Wq : (qkv == 1 ? Wk : Wv)) + (size_t)h * (ND * NDH);
    const int t = threadIdx.x;
#pragma unroll
    for (int p = 0; p < 4; ++p) {
        int u  = t + p * 256;
        int dr = u >> 4;
        int c4 = (u & 15) * 4;
        float4 v = *(const float4*)(W + (size_t)(d0 + dr) * NDH + c4);
        T[c4 + 0][dr] = f2bf(v.x);
        T[c4 + 1][dr] = f2bf(v.y);
        T[c4 + 2][dr] = f2bf(v.z);
        T[c4 + 3][dr] = f2bf(v.w);
    }
    __syncthreads();
    unsigned short* outp = Wtb + (size_t)(qkv * NH + h) * NDH * ND;
#pragma unroll
    for (int p = 0; p < 2; ++p) {
        int u  = t + p * 256;
        int dh = u >> 3;
        int sg = (u & 7) * 8;
        *(ush8*)(outp + (size_t)dh * ND + d0 + sg) = *(ush8*)&T[dh][sg];
    }
}

// ---------------------------------------------------------------------------
// QKV projection as ONE GEMM: out[m][n] = sum_d xb[m][d]*Wtb[n][d],
// m=4096, n=3072, 128x128 tile, BK=64, 4 waves (2x2 of 64x64).
// ---------------------------------------------------------------------------
__global__ __launch_bounds__(256, 2) void k_qkv_mfma(
    const unsigned short* __restrict__ xb, const unsigned short* __restrict__ Wtb,
    const float* __restrict__ bq, const float* __restrict__ bk,
    const float* __restrict__ bv,
    unsigned short* __restrict__ Qb, unsigned short* __restrict__ Kb,
    unsigned short* __restrict__ Vtb)
{
    __shared__ unsigned short LB[2 * 128 * 64];   // As|Bs, reused as TS[128][128]
    unsigned short* As = LB;
    unsigned short* Bs = LB + 128 * 64;

    const int mt = blockIdx.x;   // 0..31
    const int nt = blockIdx.y;   // 0..23
    const int qkv = nt >> 3;
    const int t = threadIdx.x, w = t >> 6, lane = t & 63;
    const int lr = lane & 15, lg = lane >> 4;
    const int wm = (w >> 1) * 64, wn = (w & 1) * 64;
    const int swz = (lr & 7) << 3;
    const int rA = lane >> 3, cg = (lane & 7) * 8;

    f32x4 acc[4][4] = {};

    for (int k0 = 0; k0 < ND; k0 += 64) {
        __syncthreads();
#pragma unroll
        for (int i = 0; i < 4; ++i) {            // 16 chunks each, 4/wave
            int c  = w * 4 + i;
            int r  = c * 8 + rA;
            int gc = cg ^ ((r & 7) << 3);
            gload16(xb  + (size_t)(mt * 128 + r) * ND + k0 + gc, &As[c * 512]);
            gload16(Wtb + (size_t)(nt * 128 + r) * ND + k0 + gc, &Bs[c * 512]);
        }
        __syncthreads();

        bhalf8 av[4][2], bw[4][2];
#pragma unroll
        for (int f = 0; f < 4; ++f)
#pragma unroll
            for (int ks = 0; ks < 2; ++ks) {
                int c = (ks * 32 + lg * 8) ^ swz;
                av[f][ks] = *(const bhalf8*)&As[(wm + f * 16 + lr) * 64 + c];
                bw[f][ks] = *(const bhalf8*)&Bs[(wn + f * 16 + lr) * 64 + c];
            }
#pragma unroll
        for (int mf = 0; mf < 4; ++mf)
#pragma unroll
            for (int nf = 0; nf < 4; ++nf) {
                acc[mf][nf] = MFMA_BF16(av[mf][0], bw[nf][0], acc[mf][nf]);
                acc[mf][nf] = MFMA_BF16(av[mf][1], bw[nf][1], acc[mf][nf]);
            }
    }

    const float* bias = (qkv == 0 ? bq : (qkv == 1 ? bk : bv));
    const int nb = (nt & 7) * 128;
    float bi[4];
#pragma unroll
    for (int nf = 0; nf < 4; ++nf) bi[nf] = bias[nb + wn + nf * 16 + lr];

    __syncthreads();                    // done with As/Bs
    unsigned short* TS = LB;            // [128][128], xor-swizzled

    if (qkv < 2) {
#pragma unroll
        for (int mf = 0; mf < 4; ++mf)
#pragma unroll
            for (int nf = 0; nf < 4; ++nf)
#pragma unroll
                for (int r = 0; r < 4; ++r) {
                    int m = wm + mf * 16 + lg * 4 + r;
                    int n = (wn + nf * 16 + lr) ^ ((m & 7) << 3);
                    TS[m * 128 + n] = f2bf(acc[mf][nf][r] + bi[nf]);
                }
        __syncthreads();
        unsigned short* outp = (qkv == 0 ? Qb : Kb);
#pragma unroll
        for (int p = 0; p < 8; ++p) {
            int u = t + p * 256;
            int r = u >> 4, sg = (u & 15) * 8;
            ush8 v = *(const ush8*)&TS[r * 128 + (sg ^ ((r & 7) << 3))];
            int m = mt * 128 + r;
            int b = m >> 11, l = m & (NL - 1);
            int n = nb + sg;
            int h = n >> 6, dh = n & 63;
            *(ush8*)(outp + ((size_t)(b * NH + h) * NL + l) * NDH + dh) = v;
        }
    } else {
#pragma unroll
        for (int mf = 0; mf < 4; ++mf)
#pragma unroll
            for (int nf = 0; nf < 4; ++nf) {
                int n = wn + nf * 16 + lr;
                int mc = (wm + mf * 16 + lg * 4) ^ ((n & 7) << 3);
                ush4 pk;
#pragma unroll
                for (int r = 0; r < 4; ++r) pk[r] = f2bf(acc[mf][nf][r] + bi[nf]);
                *(ush4*)&TS[n * 128 + mc] = pk;
            }
        __syncthreads();
#pragma unroll
        for (int p = 0; p < 8; ++p) {
            int u = t + p * 256;
            int r = u >> 4, sg = (u & 15) * 8;
            ush8 v = *(const ush8*)&TS[r * 128 + (sg ^ ((r & 7) << 3))];
            int n = nb + r;
            int h = n >> 6, dh = n & 63;
            int m0 = mt * 128 + sg;
            int b = m0 >> 11, l0 = m0 & (NL - 1);
            *(ush8*)(Vtb + ((size_t)(b * NH + h) * NDH + dh) * NL + l0) = v;
        }
    }
}

// ---------------------------------------------------------------------------
// Column stats + V prescale. 512 thr, 8 waves = 4 jg (32 j each) x 2 ig (32 i).
// K-frags hoisted to registers (j-tile fixed per block). i-step 64, 32 iters.
// Z[bh][j] = sum_i exp(SCALE*Q_i.K_j); then Vt[bh][dh][j] *= 1/Z_j in place.
// ---------------------------------------------------------------------------
__global__ __launch_bounds__(512) void k_colsum_mfma(
    const unsigned short* __restrict__ Qb, const unsigned short* __restrict__ Kb,
    unsigned short* __restrict__ Vtb)
{
    __shared__ unsigned short Ks[128 * 64];   // [j][d], xor-swz
    __shared__ unsigned short Qs[64 * 64];    // [i][d], xor-swz
    __shared__ float zpart[2][128];
    __shared__ float rzbuf[128];

    const int jt = blockIdx.x;    // 0..15
    const int bh = blockIdx.y;    // 0..31
    const unsigned short* Qp = Qb + (size_t)bh * NL * NDH;
    const unsigned short* Kp = Kb + (size_t)bh * NL * NDH;
    const int t = threadIdx.x, w = t >> 6, lane = t & 63;
    const int lr = lane & 15, lg = lane >> 4;
    const int jg = w & 3;    // 32-j group
    const int ig = w >> 2;   // 32-i group within the 64-i step
    const int swz = (lr & 7) << 3;
    const int rA = lane >> 3, cg = (lane & 7) * 8;

    // K tile 128x64 staged once: 16 chunks, 2/wave
#pragma unroll
    for (int i = 0; i < 2; ++i) {
        int c  = w * 2 + i;
        int r  = c * 8 + rA;
        int gc = cg ^ ((r & 7) << 3);
        gload16(Kp + (size_t)(jt * 128 + r) * NDH + gc, &Ks[c * 512]);
    }
    __syncthreads();
    // hoist K fragments (loop-invariant)
    bhalf8 kf[2][2];
#pragma unroll
    for (int jf = 0; jf < 2; ++jf)
#pragma unroll
        for (int ks = 0; ks < 2; ++ks)
            kf[jf][ks] = *(const bhalf8*)&Ks[(jg * 32 + jf * 16 + lr) * 64 +
                                            ((ks * 32 + lg * 8) ^ swz)];

    float zacc[2][4] = {};

    for (int it = 0; it < 32; ++it) {
        __syncthreads();                 // prev Qs reads done
        {                                // Q tile 64x64: 8 chunks, 1/wave
            int r  = w * 8 + rA;
            int gc = cg ^ ((r & 7) << 3);
            gload16(Qp + (size_t)(it * 64 + r) * NDH + gc, &Qs[w * 512]);
        }
        __syncthreads();                 // staged

#pragma unroll
        for (int ii = 0; ii < 2; ++ii) {
            bhalf8 q0 = *(const bhalf8*)&Qs[(ig * 32 + ii * 16 + lr) * 64 + ((lg * 8) ^ swz)];
            bhalf8 q1 = *(const bhalf8*)&Qs[(ig * 32 + ii * 16 + lr) * 64 + ((32 + lg * 8) ^ swz)];
#pragma unroll
            for (int jf = 0; jf < 2; ++jf) {
                f32x4 s = {};
                s = MFMA_BF16(kf[jf][0], q0, s);
                s = MFMA_BF16(kf[jf][1], q1, s);
#pragma unroll
                for (int r = 0; r < 4; ++r) zacc[jf][r] += __expf(s[r] * SCALE);
            }
        }
    }

    // reduce over the 16 lanes holding different i, then across ig via LDS
#pragma unroll
    for (int jf = 0; jf < 2; ++jf)
#pragma unroll
        for (int r = 0; r < 4; ++r) {
            float v = zacc[jf][r];
            v += __shfl_xor(v, 1);
            v += __shfl_xor(v, 2);
            v += __shfl_xor(v, 4);
            v += __shfl_xor(v, 8);
            if (lr == 0) zpart[ig][jg * 32 + jf * 16 + lg * 4 + r] = v;
        }
    __syncthreads();
    if (t < 128) rzbuf[t] = 1.0f / (zpart[0][t] + zpart[1][t]);
    __syncthreads();

    // scale Vt[bh][0..63][jt*128 .. +128) in place: 512 thr x 16 elems
    unsigned short* Vp = Vtb + (size_t)bh * NDH * NL + jt * 128;
    {
        int dh = t >> 3, jj = (t & 7) * 16;
        unsigned short* vp = Vp + (size_t)dh * NL + jj;
        ush8 v0 = *(const ush8*)vp;
        ush8 v1 = *(const ush8*)(vp + 8);
        float4 z0 = *(const float4*)&rzbuf[jj];
        float4 z1 = *(const float4*)&rzbuf[jj + 4];
        float4 z2 = *(const float4*)&rzbuf[jj + 8];
        float4 z3 = *(const float4*)&rzbuf[jj + 12];
        uint4 o0, o1;
        o0.x = pack_bf16(bf2f(v0[0]) * z0.x, bf2f(v0[1]) * z0.y);
        o0.y = pack_bf16(bf2f(v0[2]) * z0.z, bf2f(v0[3]) * z0.w);
        o0.z = pack_bf16(bf2f(v0[4]) * z1.x, bf2f(v0[5]) * z1.y);
        o0.w = pack_bf16(bf2f(v0[6]) * z1.z, bf2f(v0[7]) * z1.w);
        o1.x = pack_bf16(bf2f(v1[0]) * z2.x, bf2f(v1[1]) * z2.y);
        o1.y = pack_bf16(bf2f(v1[2]) * z2.z, bf2f(v1[3]) * z2.w);
        o1.z = pack_bf16(bf2f(v1[4]) * z3.x, bf2f(v1[5]) * z3.y);
        o1.w = pack_bf16(bf2f(v1[6]) * z3.z, bf2f(v1[7]) * z3.w);
        *(uint4*)vp = o0;
        *(uint4*)(vp + 8) = o1;
    }
}

// ---------------------------------------------------------------------------
// O[i][dh] = sum_j exp(SCALE*S_ij) * Vscaled[j][dh]. 512 thr, 8 waves.
// S phase: 8 waves as 2 jg (32 j) x 4 ig (32 i), Q-frags hoisted in regs.
// PV phase: 4 waves, each 32 i x 64 dh over full j=64 (no cross-wave reduce).
// ---------------------------------------------------------------------------
__global__ __launch_bounds__(512) void k_av_mfma(
    const unsigned short* __restrict__ Qb, const unsigned short* __restrict__ Kb,
    const unsigned short* __restrict__ Vtb, unsigned short* __restrict__ AOb)
{
    __shared__ unsigned short Qs[128 * 64];   // [i][d]  xor-swz
    __shared__ unsigned short Ks[64 * 64];    // [j][d]  xor-swz
    __shared__ unsigned short Vts[64 * 64];   // [dh][j] xor-swz (prescaled)
    __shared__ unsigned short Ps[128 * 64];   // [i][j]  xor-swz

    const int it = blockIdx.x;   // 0..15
    const int bh = blockIdx.y;   // 0..31
    const int b = bh >> 4, h = bh & 15;
    const unsigned short* Qp = Qb  + (size_t)bh * NL * NDH;
    const unsigned short* Kp = Kb  + (size_t)bh * NL * NDH;
    const unsigned short* Vp = Vtb + (size_t)bh * NDH * NL;

    const int t = threadIdx.x, w = t >> 6, lane = t & 63;
    const int lr = lane & 15, lg = lane >> 4;
    const int jgS = w & 1;    // S: 32-j half
    const int igS = w >> 1;   // S: 32-i group
    const int swz = (lr & 7) << 3;
    const int rA = lane >> 3, cg = (lane & 7) * 8;

    // Q tile 128x64 staged once: 16 chunks, 2/wave
#pragma unroll
    for (int i = 0; i < 2; ++i) {
        int c  = w * 2 + i;
        int r  = c * 8 + rA;
        int gc = cg ^ ((r & 7) << 3);
        gload16(Qp + (size_t)(it * 128 + r) * NDH + gc, &Qs[c * 512]);
    }
    __syncthreads();
    // hoist Q fragments (loop-invariant)
    bhalf8 qf[2][2];
#pragma unroll
    for (int ii = 0; ii < 2; ++ii)
#pragma unroll
        for (int ks = 0; ks < 2; ++ks)
            qf[ii][ks] = *(const bhalf8*)&Qs[(igS * 32 + ii * 16 + lr) * 64 +
                                            ((ks * 32 + lg * 8) ^ swz)];

    f32x4 oacc[2][4] = {};   // used by waves 0..3 (PV)

    for (int jt = 0; jt < 32; ++jt) {
        __syncthreads();                 // prev-iter PV reads of Ks/Vts/Ps done
        {                                // K and Vt: 8 chunks each, 1/wave
            int r  = w * 8 + rA;
            int gc = cg ^ ((r & 7) << 3);
            gload16(Kp + (size_t)(jt * 64 + r) * NDH + gc, &Ks[w * 512]);
            gload16(Vp + (size_t)r * NL + jt * 64 + gc,    &Vts[w * 512]);
        }
        __syncthreads();                 // staged

        // S phase: wave computes [2 jf x 16 j] x [2 ii x 16 i] -> P
#pragma unroll
        for (int jf = 0; jf < 2; ++jf) {
            bhalf8 k0 = *(const bhalf8*)&Ks[(jgS * 32 + jf * 16 + lr) * 64 + ((lg * 8) ^ swz)];
            bhalf8 k1 = *(const bhalf8*)&Ks[(jgS * 32 + jf * 16 + lr) * 64 + ((32 + lg * 8) ^ swz)];
#pragma unroll
            for (int ii = 0; ii < 2; ++ii) {
                f32x4 s = {};
                s = MFMA_BF16(k0, qf[ii][0], s);
                s = MFMA_BF16(k1, qf[ii][1], s);
                uint2 pk;
                pk.x = pack_bf16(__expf(s[0] * SCALE), __expf(s[1] * SCALE));
                pk.y = pack_bf16(__expf(s[2] * SCALE), __expf(s[3] * SCALE));
                int i = igS * 32 + ii * 16 + lr;
                *(uint2*)&Ps[i * 64 + ((jgS * 32 + jf * 16 + lg * 4) ^ ((i & 7) << 3))] = pk;
            }
        }
        __syncthreads();                 // P visible to PV waves

        // PV phase: waves 0..3, wave w owns i [w*32, +32), full j=64
        if (w < 4) {
            bhalf8 pa[2][2];
#pragma unroll
            for (int iif = 0; iif < 2; ++iif)
#pragma unroll
                for (int ks = 0; ks < 2; ++ks)
                    pa[iif][ks] = *(const bhalf8*)&Ps[(w * 32 + iif * 16 + lr) * 64 +
                                                     ((ks * 32 + lg * 8) ^ swz)];
#pragma unroll
            for (int nf = 0; nf < 4; ++nf) {
                bhalf8 v0 = *(const bhalf8*)&Vts[(nf * 16 + lr) * 64 + ((lg * 8) ^ swz)];
                bhalf8 v1 = *(const bhalf8*)&Vts[(nf * 16 + lr) * 64 + ((32 + lg * 8) ^ swz)];
#pragma unroll
                for (int iif = 0; iif < 2; ++iif) {
                    oacc[iif][nf] = MFMA_BF16(pa[iif][0], v0, oacc[iif][nf]);
                    oacc[iif][nf] = MFMA_BF16(pa[iif][1], v1, oacc[iif][nf]);
                }
            }
        }
    }

    // epilogue: PV waves pack into Ps (transposed layout), all threads write AO
    __syncthreads();
    if (w < 4) {
#pragma unroll
        for (int iif = 0; iif < 2; ++iif)
#pragma unroll
            for (int nf = 0; nf < 4; ++nf)
#pragma unroll
                for (int r = 0; r < 4; ++r) {
                    int li  = w * 32 + iif * 16 + lg * 4 + r;
                    int dhc = (nf * 16 + lr) ^ ((li & 7) << 3);
                    Ps[li * 64 + dhc] = f2bf(oacc[iif][nf][r]);
                }
    }
    __syncthreads();
    {
        int r = t >> 2, sgq = (t & 3) * 16;
        int sz2 = (r & 7) << 3;
        ush8 v0 = *(const ush8*)&Ps[r * 64 + (sgq ^ sz2)];
        ush8 v1 = *(const ush8*)&Ps[r * 64 + ((sgq + 8) ^ sz2)];
        unsigned short* op = AOb + ((size_t)(b * NL + it * 128 + r)) * ND + h * NDH + sgq;
        *(ush8*)op = v0;
        *(ush8*)(op + 8) = v1;
    }
}

// ---------------------------------------------------------------------------
// Output projection: y[m][e] = sum_d AO[m][d]*WO[e][d] + bO[e].
// 64(m) x 128(e) tile, BK=64, 4 waves each own 64m x 32e. Grid 512.
// ---------------------------------------------------------------------------
__global__ __launch_bounds__(256, 2) void k_oproj_mfma(
    const unsigned short* __restrict__ AOb, const unsigned short* __restrict__ WOb,
    const float* __restrict__ bO, float* __restrict__ y)
{
    __shared__ unsigned short As[64 * 64];    // AO rows m
    __shared__ unsigned short Bs[128 * 64];   // WO rows e

    const int mt = blockIdx.x;   // 0..63
    const int nt = blockIdx.y;   // 0..7
    const int t = threadIdx.x, w = t >> 6, lane = t & 63;
    const int lr = lane & 15, lg = lane >> 4;
    const int wn = w * 32;
    const int swz = (lr & 7) << 3;
    const int rA = lane >> 3, cg = (lane & 7) * 8;

    f32x4 acc[4][2] = {};

    for (int k0 = 0; k0 < ND; k0 += 64) {
        __syncthreads();
#pragma unroll
        for (int i = 0; i < 2; ++i) {            // A: 8 chunks, 2/wave
            int c  = w * 2 + i;
            int r  = c * 8 + rA;
            int gc = cg ^ ((r & 7) << 3);
            gload16(AOb + (size_t)(mt * 64 + r) * ND + k0 + gc, &As[c * 512]);
        }
#pragma unroll
        for (int i = 0; i < 4; ++i) {            // B: 16 chunks, 4/wave
            int c  = w * 4 + i;
            int r  = c * 8 + rA;
            int gc = cg ^ ((r & 7) << 3);
            gload16(WOb + (size_t)(nt * 128 + r) * ND + k0 + gc, &Bs[c * 512]);
        }
        __syncthreads();

        bhalf8 bw[2][2];
#pragma unroll
        for (int nf = 0; nf < 2; ++nf)
#pragma unroll
            for (int ks = 0; ks < 2; ++ks)
                bw[nf][ks] = *(const bhalf8*)&Bs[(wn + nf * 16 + lr) * 64 +
                                                ((ks * 32 + lg * 8) ^ swz)];
#pragma unroll
        for (int mf = 0; mf < 4; ++mf) {
            bhalf8 a0 = *(const bhalf8*)&As[(mf * 16 + lr) * 64 + ((lg * 8) ^ swz)];
            bhalf8 a1 = *(const bhalf8*)&As[(mf * 16 + lr) * 64 + ((32 + lg * 8) ^ swz)];
#pragma unroll
            for (int nf = 0; nf < 2; ++nf) {
                acc[mf][nf] = MFMA_BF16(a0, bw[nf][0], acc[mf][nf]);
                acc[mf][nf] = MFMA_BF16(a1, bw[nf][1], acc[mf][nf]);
            }
        }
    }

#pragma unroll
    for (int mf = 0; mf < 4; ++mf)
#pragma unroll
        for (int nf = 0; nf < 2; ++nf) {
            int e = nt * 128 + wn + nf * 16 + lr;
            float bo = bO[e];
#pragma unroll
            for (int r = 0; r < 4; ++r) {
                int m = mt * 64 + mf * 16 + lg * 4 + r;
                y[(size_t)m * ND + e] = acc[mf][nf][r] + bo;
            }
        }
}

// ---------------------------------------------------------------------------
extern "C" void kernel_launch(void* const* d_in, const int* in_sizes, int n_in,
                              void* d_out, int out_size, void* d_ws, size_t ws_size,
                              hipStream_t stream)
{
    const float* x  = (const float*)d_in[0];
    const float* Wq = (const float*)d_in[1];
    const float* bq = (const float*)d_in[2];
    const float* Wk = (const float*)d_in[3];
    const float* bk = (const float*)d_in[4];
    const float* Wv = (const float*)d_in[5];
    const float* bv = (const float*)d_in[6];
    const float* WO = (const float*)d_in[7];
    const float* bO = (const float*)d_in[8];
    float* y = (float*)d_out;

    unsigned short* xb  = (unsigned short*)d_ws;     // 4,194,304 (8 MB)
    unsigned short* Wtb = xb  + 4194304;             // 3,145,728 (6 MB)
    unsigned short* WOb = Wtb + 3145728;             // 1,048,576 (2 MB)
    unsigned short* Qb  = WOb + 1048576;             // 4,194,304 (8 MB)
    unsigned short* Kb  = Qb  + 4194304;             // 4,194,304 (8 MB)
    unsigned short* Vtb = Kb  + 4194304;             // 4,194,304 (8 MB)
    unsigned short* AOb = Vtb + 4194304;             // 4,194,304 (8 MB)

    hipLaunchKernelGGL(k_cvt,         dim3(2560),   dim3(256), 0, stream, x, WO, xb, WOb);
    hipLaunchKernelGGL(k_cvt_wt,      dim3(16, 48), dim3(256), 0, stream, Wq, Wk, Wv, Wtb);
    hipLaunchKernelGGL(k_qkv_mfma,    dim3(32, 24), dim3(256), 0, stream,
                       xb, Wtb, bq, bk, bv, Qb, Kb, Vtb);
    hipLaunchKernelGGL(k_colsum_mfma, dim3(16, 32), dim3(512), 0, stream, Qb, Kb, Vtb);
    hipLaunchKernelGGL(k_av_mfma,     dim3(16, 32), dim3(512), 0, stream, Qb, Kb, Vtb, AOb);
    hipLaunchKernelGGL(k_oproj_mfma,  dim3(64, 8),  dim3(256), 0, stream, AOb, WOb, bO, y);
}